// Round 2
// baseline (1039.230 us; speedup 1.0000x reference)
//
#include <hip/hip_runtime.h>
#include <hip/hip_bf16.h>
#include <math.h>

typedef unsigned short u16;
typedef unsigned int   u32;
typedef float f4   __attribute__((ext_vector_type(4)));
typedef float f32x4 __attribute__((ext_vector_type(4)));
typedef __bf16 bf16x8 __attribute__((ext_vector_type(8)));

#define BDIM 16
#define HDIM 64
#define WDIM 64
#define CDIM 256
#define NHEAD 8
#define DHEAD 32
#define FDIM 1024
#define MROWS (BDIM*HDIM*WDIM)   // 65536

__device__ inline float blo(u32 u){ return __uint_as_float(u << 16); }
__device__ inline float bhi(u32 u){ return __uint_as_float(u & 0xffff0000u); }

__device__ inline u16 f2bf(float f){
    __bf16 h = (__bf16)f;
    return __builtin_bit_cast(unsigned short, h);
}
__device__ inline u32 pack2(float lo, float hi){
    return (u32)f2bf(lo) | ((u32)f2bf(hi) << 16);
}
__device__ inline void unp8(uint4 u, float* d){
    d[0]=blo(u.x); d[1]=bhi(u.x); d[2]=blo(u.y); d[3]=bhi(u.y);
    d[4]=blo(u.z); d[5]=bhi(u.z); d[6]=blo(u.w); d[7]=bhi(u.w);
}

// ---------------- weight convert + transpose: dst[n*K+k] = bf16(src[k*N+n]) ---
__global__ __launch_bounds__(256)
void convert_weights_kernel(const float* __restrict__ wq, const float* __restrict__ wk,
                            const float* __restrict__ wv, const float* __restrict__ wo,
                            const float* __restrict__ fc1, const float* __restrict__ fc2,
                            u16* __restrict__ wT)
{
    int i = blockIdx.x * 256 + threadIdx.x;      // 0 .. 786431
    const float* src; int K, N, off;
    if (i < 262144) {                 // wq, wk, wv, wo: each 256x256
        int m = i >> 16;
        src = (m==0) ? wq : (m==1) ? wk : (m==2) ? wv : wo;
        K = 256; N = 256; off = i & 65535;
    } else if (i < 524288) {          // fc1: K=256 N=1024
        src = fc1; K = 256; N = 1024; off = i - 262144;
    } else {                          // fc2: K=1024 N=256
        src = fc2; K = 1024; N = 256; off = i - 524288;
    }
    int k = off % K, n = off / K;
    wT[i] = f2bf(src[(size_t)k * N + n]);
}

// ---------------- 3x3 depthwise conv + residual (fp32) -----------------------
__global__ __launch_bounds__(256)
void posconv_kernel(const float* __restrict__ x, const float* __restrict__ w,
                    const float* __restrict__ bias, float* __restrict__ out)
{
    int idx = blockIdx.x * 256 + threadIdx.x;    // B*H*W*(C/4)
    int c = (idx & 63) * 4;
    int p = idx >> 6;
    int wp = p & 63, hp = (p >> 6) & 63, bp = p >> 12;
    f4 acc = *reinterpret_cast<const f4*>(bias + c);
    #pragma unroll
    for (int kh = 0; kh < 3; kh++){
        int hh = hp + kh - 1; if ((unsigned)hh >= 64u) continue;
        #pragma unroll
        for (int kw = 0; kw < 3; kw++){
            int ww = wp + kw - 1; if ((unsigned)ww >= 64u) continue;
            f4 xv = *reinterpret_cast<const f4*>(x + (((size_t)(bp*64 + hh))*64 + ww)*256 + c);
            f4 wv = *reinterpret_cast<const f4*>(w + (size_t)(kh*3 + kw)*256 + c);
            acc += xv * wv;
        }
    }
    f4 ctr = *reinterpret_cast<const f4*>(x + (size_t)p*256 + c);
    *reinterpret_cast<f4*>(out + (size_t)p*256 + c) = ctr + acc;
}

// ---------------- 5x5 depthwise conv on bf16 v -> bf16 lepe ------------------
__global__ __launch_bounds__(256)
void lepe_kernel(const u16* __restrict__ v, const float* __restrict__ w,
                 const float* __restrict__ bias, u16* __restrict__ out)
{
    int idx = blockIdx.x * 256 + threadIdx.x;    // Bc*H*W*(C/8)
    int c = (idx & 31) * 8;
    int p = idx >> 5;
    int wp = p & 63, hp = (p >> 6) & 63, bp = p >> 12;
    float acc[8];
    #pragma unroll
    for (int j = 0; j < 8; j++) acc[j] = bias[c + j];
    #pragma unroll
    for (int kh = 0; kh < 5; kh++){
        int hh = hp + kh - 2; if ((unsigned)hh >= 64u) continue;
        #pragma unroll
        for (int kw = 0; kw < 5; kw++){
            int ww = wp + kw - 2; if ((unsigned)ww >= 64u) continue;
            uint4 u = *reinterpret_cast<const uint4*>(v + (((size_t)(bp*64 + hh))*64 + ww)*256 + c);
            float xv[8]; unp8(u, xv);
            const float* wr = w + (size_t)(kh*5 + kw)*256 + c;
            #pragma unroll
            for (int j = 0; j < 8; j++) acc[j] += xv[j] * wr[j];
        }
    }
    uint4 r;
    r.x = pack2(acc[0],acc[1]); r.y = pack2(acc[2],acc[3]);
    r.z = pack2(acc[4],acc[5]); r.w = pack2(acc[6],acc[7]);
    *reinterpret_cast<uint4*>(out + (size_t)p*256 + c) = r;
}

// ---------------- LayerNorm (fp32 in, bf16 out), 4 rows/block (1 per wave) ---
__global__ __launch_bounds__(256)
void ln_kernel(const float* __restrict__ x, const float* __restrict__ g,
               const float* __restrict__ b, u16* __restrict__ y)
{
    int wid = threadIdx.x >> 6, lane = threadIdx.x & 63;
    size_t row = (size_t)blockIdx.x * 4 + wid;
    f4 v = reinterpret_cast<const f4*>(x + row*256)[lane];
    float s  = v.x + v.y + v.z + v.w;
    float q2 = v.x*v.x + v.y*v.y + v.z*v.z + v.w*v.w;
    #pragma unroll
    for (int off = 32; off > 0; off >>= 1){
        s  += __shfl_xor(s,  off);
        q2 += __shfl_xor(q2, off);
    }
    float mean = s * (1.f/256.f);
    float var  = q2 * (1.f/256.f) - mean*mean;
    float rs   = rsqrtf(var + 1e-6f);
    f4 gv = reinterpret_cast<const f4*>(g)[lane];
    f4 bv = reinterpret_cast<const f4*>(b)[lane];
    f4 t = (v - mean) * rs;
    t = t * gv + bv;
    uint2 r;
    r.x = pack2(t.x, t.y); r.y = pack2(t.z, t.w);
    *reinterpret_cast<uint2*>(y + row*256 + (size_t)lane*4) = r;
}

// ---------------- GEMM: out[M,N] = A[M,K](bf16) @ Bt[N,K]^T(bf16) + bias -----
// EPI: 0=store bf16, 1=store bf16*scale, 2=gelu->bf16, 3=+resid -> fp32
template<int EPI>
__global__ __launch_bounds__(256)
void gemm_kernel(const u16* __restrict__ A, const u16* __restrict__ Bt,
                 const float* __restrict__ bias, const float* __restrict__ resid,
                 void* __restrict__ outp, int M, int N, int K, float scale)
{
    __shared__ u16 As[64][32];
    __shared__ u16 Bs[64][32];
    int m0 = blockIdx.x * 64, n0 = blockIdx.y * 64;
    int tid = threadIdx.x, wid = tid >> 6, lane = tid & 63;
    int lr = tid >> 2, lk = (tid & 3) * 8;
    f32x4 acc[4] = {};
    const u16* Ar = A  + (size_t)(m0 + lr) * K + lk;
    const u16* Br = Bt + (size_t)(n0 + lr) * K + lk;
    for (int k0 = 0; k0 < K; k0 += 32){
        *reinterpret_cast<uint4*>(&As[lr][lk]) = *reinterpret_cast<const uint4*>(Ar + k0);
        *reinterpret_cast<uint4*>(&Bs[lr][lk]) = *reinterpret_cast<const uint4*>(Br + k0);
        __syncthreads();
        bf16x8 av = *reinterpret_cast<const bf16x8*>(&As[wid*16 + (lane & 15)][(lane >> 4) * 8]);
        #pragma unroll
        for (int nt = 0; nt < 4; nt++){
            bf16x8 bv = *reinterpret_cast<const bf16x8*>(&Bs[nt*16 + (lane & 15)][(lane >> 4) * 8]);
            acc[nt] = __builtin_amdgcn_mfma_f32_16x16x32_bf16(av, bv, acc[nt], 0, 0, 0);
        }
        __syncthreads();
    }
    #pragma unroll
    for (int nt = 0; nt < 4; nt++){
        int col = n0 + nt*16 + (lane & 15);
        float bc = bias[col];
        #pragma unroll
        for (int r = 0; r < 4; r++){
            int row = m0 + wid*16 + ((lane >> 4) << 2) + r;
            float val = acc[nt][r] + bc;
            if constexpr (EPI == 1) val *= scale;
            if constexpr (EPI == 2) val = 0.5f * val * (1.f + erff(val * 0.70710678118654752f));
            if constexpr (EPI == 3){
                size_t o = (size_t)row * N + col;
                reinterpret_cast<float*>(outp)[o] = val + resid[o];
            } else {
                reinterpret_cast<u16*>(outp)[(size_t)row * N + col] = f2bf(val);
            }
        }
    }
}

// ---------------- W-axis attention: block = (b*H + h)*NH + head --------------
// Safe to run in-place (vo == v): each block reads only the rows it writes,
// and all reads are staged to LDS/regs before the first write.
__global__ __launch_bounds__(64)
void attn_w_kernel(const u16* __restrict__ q, const u16* __restrict__ k,
                   const u16* __restrict__ v, const float* __restrict__ mask,
                   u16* __restrict__ vo)
{
    __shared__ float kl[64][33];
    __shared__ float vl[64][33];
    int bid = blockIdx.x;
    int head = bid & 7;
    int ph = bid >> 3;                       // local b*64 + h
    int lane = threadIdx.x;                  // query row (w index)
    size_t base = (size_t)ph * 16384 + head * 32;
    {
        const uint4* kp = reinterpret_cast<const uint4*>(k + base + (size_t)lane * 256);
        const uint4* vp = reinterpret_cast<const uint4*>(v + base + (size_t)lane * 256);
        #pragma unroll
        for (int j = 0; j < 4; j++) unp8(kp[j], &kl[lane][j*8]);
        #pragma unroll
        for (int j = 0; j < 4; j++) unp8(vp[j], &vl[lane][j*8]);
    }
    float qr[32];
    {
        const uint4* qp = reinterpret_cast<const uint4*>(q + base + (size_t)lane * 256);
        #pragma unroll
        for (int j = 0; j < 4; j++) unp8(qp[j], &qr[j*8]);
    }
    __syncthreads();
    const float* mrow = mask + ((size_t)head * 64 + lane) * 64;
    float s[64];
    #pragma unroll
    for (int kk = 0; kk < 64; kk++){
        float a = 0.f;
        #pragma unroll
        for (int dd = 0; dd < 32; dd++) a += qr[dd] * kl[kk][dd];
        s[kk] = a + mrow[kk];
    }
    float mx = -1e30f;
    #pragma unroll
    for (int kk = 0; kk < 64; kk++) mx = fmaxf(mx, s[kk]);
    float sum = 0.f;
    #pragma unroll
    for (int kk = 0; kk < 64; kk++){ float p = __expf(s[kk] - mx); s[kk] = p; sum += p; }
    float inv = 1.f / sum;
    float o[32];
    #pragma unroll
    for (int dd = 0; dd < 32; dd++) o[dd] = 0.f;
    #pragma unroll
    for (int kk = 0; kk < 64; kk++){
        float p = s[kk];
        #pragma unroll
        for (int dd = 0; dd < 32; dd++) o[dd] += p * vl[kk][dd];
    }
    u32 ow[16];
    #pragma unroll
    for (int j = 0; j < 16; j++) ow[j] = pack2(o[2*j] * inv, o[2*j+1] * inv);
    uint4* op = reinterpret_cast<uint4*>(vo + base + (size_t)lane * 256);
    #pragma unroll
    for (int j = 0; j < 4; j++) op[j] = make_uint4(ow[4*j], ow[4*j+1], ow[4*j+2], ow[4*j+3]);
}

// ---------------- H-axis attention (+ lepe add): block = (b*W + w)*NH + head -
// Also in-place safe (outb == vo).
__global__ __launch_bounds__(64)
void attn_h_kernel(const u16* __restrict__ q, const u16* __restrict__ k,
                   const u16* __restrict__ vo, const float* __restrict__ mask,
                   const u16* __restrict__ lepe, u16* __restrict__ outb)
{
    __shared__ float kl[64][33];
    __shared__ float vl[64][33];
    int bid = blockIdx.x;
    int head = bid & 7;
    int pw = bid >> 3;                       // local b*64 + w
    int b = pw >> 6, wc = pw & 63;
    int lane = threadIdx.x;                  // query row (h index)
    size_t base = (size_t)b * 1048576 + (size_t)wc * 256 + head * 32;
    const size_t RS = 16384;                 // row stride along H
    {
        const uint4* kp = reinterpret_cast<const uint4*>(k  + base + (size_t)lane * RS);
        const uint4* vp = reinterpret_cast<const uint4*>(vo + base + (size_t)lane * RS);
        #pragma unroll
        for (int j = 0; j < 4; j++) unp8(kp[j], &kl[lane][j*8]);
        #pragma unroll
        for (int j = 0; j < 4; j++) unp8(vp[j], &vl[lane][j*8]);
    }
    float qr[32];
    {
        const uint4* qp = reinterpret_cast<const uint4*>(q + base + (size_t)lane * RS);
        #pragma unroll
        for (int j = 0; j < 4; j++) unp8(qp[j], &qr[j*8]);
    }
    float lp[32];
    {
        const uint4* lpp = reinterpret_cast<const uint4*>(lepe + base + (size_t)lane * RS);
        #pragma unroll
        for (int j = 0; j < 4; j++) unp8(lpp[j], &lp[j*8]);
    }
    __syncthreads();
    const float* mrow = mask + ((size_t)head * 64 + lane) * 64;
    float s[64];
    #pragma unroll
    for (int kk = 0; kk < 64; kk++){
        float a = 0.f;
        #pragma unroll
        for (int dd = 0; dd < 32; dd++) a += qr[dd] * kl[kk][dd];
        s[kk] = a + mrow[kk];
    }
    float mx = -1e30f;
    #pragma unroll
    for (int kk = 0; kk < 64; kk++) mx = fmaxf(mx, s[kk]);
    float sum = 0.f;
    #pragma unroll
    for (int kk = 0; kk < 64; kk++){ float p = __expf(s[kk] - mx); s[kk] = p; sum += p; }
    float inv = 1.f / sum;
    float o[32];
    #pragma unroll
    for (int dd = 0; dd < 32; dd++) o[dd] = 0.f;
    #pragma unroll
    for (int kk = 0; kk < 64; kk++){
        float p = s[kk];
        #pragma unroll
        for (int dd = 0; dd < 32; dd++) o[dd] += p * vl[kk][dd];
    }
    u32 ow[16];
    #pragma unroll
    for (int j = 0; j < 16; j++)
        ow[j] = pack2(o[2*j] * inv + lp[2*j], o[2*j+1] * inv + lp[2*j+1]);
    uint4* op = reinterpret_cast<uint4*>(outb + base + (size_t)lane * RS);
    #pragma unroll
    for (int j = 0; j < 4; j++) op[j] = make_uint4(ow[4*j], ow[4*j+1], ow[4*j+2], ow[4*j+3]);
}

extern "C" void kernel_launch(void* const* d_in, const int* in_sizes, int n_in,
                              void* d_out, int out_size, void* d_ws, size_t ws_size,
                              hipStream_t stream)
{
    const float* x      = (const float*)d_in[0];
    const float* mask_h = (const float*)d_in[1];
    const float* mask_w = (const float*)d_in[2];
    const float* pos_w  = (const float*)d_in[3];
    const float* pos_b  = (const float*)d_in[4];
    const float* ln1_g  = (const float*)d_in[5];
    const float* ln1_b  = (const float*)d_in[6];
    const float* wq     = (const float*)d_in[7];
    const float* bq     = (const float*)d_in[8];
    const float* wk     = (const float*)d_in[9];
    const float* bk     = (const float*)d_in[10];
    const float* wv     = (const float*)d_in[11];
    const float* bv     = (const float*)d_in[12];
    const float* lepe_w = (const float*)d_in[13];
    const float* lepe_b = (const float*)d_in[14];
    const float* wo     = (const float*)d_in[15];
    const float* bo     = (const float*)d_in[16];
    const float* ln2_g  = (const float*)d_in[17];
    const float* ln2_b  = (const float*)d_in[18];
    const float* fc1_w  = (const float*)d_in[19];
    const float* fc1_b  = (const float*)d_in[20];
    const float* fc2_w  = (const float*)d_in[21];
    const float* fc2_b  = (const float*)d_in[22];

    const size_t MB = 1u << 20;
    // x1/x2 residual lives in d_out (fp32, 64 MiB) — all its RMW is element-wise.
    float* x1 = (float*)d_out;

    // Pick largest batch-chunk Bc in {16,8,4,2,1} such that
    // ws requirement = 2 MiB (weights) + 10*Bc MiB fits.
    int Bc = 1;
    for (int c = 16; c >= 1; c >>= 1){
        if (ws_size >= (2 + 10 * (size_t)c) * MB) { Bc = c; break; }
    }

    char* ws = (char*)d_ws;
    u16* wT  = (u16*)ws;                       // 1.5 MiB of bf16 transposed weights
    u16* wqT = wT, *wkT = wT + 65536, *wvT = wT + 131072, *woT = wT + 196608;
    u16* fc1T = wT + 262144, *fc2T = wT + 524288;
    size_t cb = (size_t)Bc * 2 * MB;           // bytes per bf16 chunk buffer
    u16* y   = (u16*)(ws + 2*MB);
    u16* qb  = (u16*)(ws + 2*MB + cb);
    u16* kb  = (u16*)(ws + 2*MB + 2*cb);
    u16* vb  = (u16*)(ws + 2*MB + 3*cb);
    u16* lep = (u16*)(ws + 2*MB + 4*cb);
    u16* hb  = qb;                             // MLP hidden overlays q,k,v,lep (4*cb)

    dim3 blk(256);
    convert_weights_kernel<<<3072, blk, 0, stream>>>(wq, wk, wv, wo, fc1_w, fc2_w, wT);
    posconv_kernel<<<16384, blk, 0, stream>>>(x, pos_w, pos_b, x1);

    const int nchunk = 16 / Bc;
    const int R = Bc * 4096;                   // rows per chunk
    for (int c = 0; c < nchunk; c++){
        float* xc = x1 + (size_t)c * R * 256;
        dim3 gq(R/64, 4), gf(R/64, 16);
        ln_kernel<<<R/4, blk, 0, stream>>>(xc, ln1_g, ln1_b, y);
        gemm_kernel<0><<<gq, blk, 0, stream>>>(y, wqT, bq, nullptr, qb, R, 256, 256, 1.f);
        gemm_kernel<1><<<gq, blk, 0, stream>>>(y, wkT, bk, nullptr, kb, R, 256, 256, 0.17677669529663687f);
        gemm_kernel<0><<<gq, blk, 0, stream>>>(y, wvT, bv, nullptr, vb, R, 256, 256, 1.f);
        lepe_kernel<<<Bc*512, blk, 0, stream>>>(vb, lepe_w, lepe_b, lep);
        attn_w_kernel<<<Bc*512, 64, 0, stream>>>(qb, kb, vb, mask_w, vb);      // vo in-place
        attn_h_kernel<<<Bc*512, 64, 0, stream>>>(qb, kb, vb, mask_h, lep, vb); // attn in-place
        gemm_kernel<3><<<gq, blk, 0, stream>>>(vb, woT, bo, xc, (void*)xc, R, 256, 256, 1.f);
        ln_kernel<<<R/4, blk, 0, stream>>>(xc, ln2_g, ln2_b, y);
        gemm_kernel<2><<<gf, blk, 0, stream>>>(y, fc1T, fc1_b, nullptr, hb, R, 1024, 256, 1.f);
        gemm_kernel<3><<<gq, blk, 0, stream>>>(hb, fc2T, fc2_b, xc, (void*)xc, R, 256, 1024, 1.f);
    }
}

// Round 3
// 990.244 us; speedup vs baseline: 1.0495x; 1.0495x over previous
//
#include <hip/hip_runtime.h>
#include <hip/hip_bf16.h>
#include <math.h>

typedef unsigned short u16;
typedef unsigned int   u32;
typedef float f4   __attribute__((ext_vector_type(4)));
typedef float f32x4 __attribute__((ext_vector_type(4)));
typedef __bf16 bf16x8 __attribute__((ext_vector_type(8)));

#define BDIM 16
#define HDIM 64
#define WDIM 64
#define CDIM 256
#define NHEAD 8
#define DHEAD 32
#define FDIM 1024
#define MROWS (BDIM*HDIM*WDIM)   // 65536

__device__ inline float blo(u32 u){ return __uint_as_float(u << 16); }
__device__ inline float bhi(u32 u){ return __uint_as_float(u & 0xffff0000u); }

__device__ inline u16 f2bf(float f){
    __bf16 h = (__bf16)f;
    return __builtin_bit_cast(unsigned short, h);
}
__device__ inline u32 pack2(float lo, float hi){
    return (u32)f2bf(lo) | ((u32)f2bf(hi) << 16);
}
__device__ inline void unp8(uint4 u, float* d){
    d[0]=blo(u.x); d[1]=bhi(u.x); d[2]=blo(u.y); d[3]=bhi(u.y);
    d[4]=blo(u.z); d[5]=bhi(u.z); d[6]=blo(u.w); d[7]=bhi(u.w);
}

// ---------------- weight convert + transpose: dst[n*K+k] = bf16(src[k*N+n]) ---
__global__ __launch_bounds__(256)
void convert_weights_kernel(const float* __restrict__ wq, const float* __restrict__ wk,
                            const float* __restrict__ wv, const float* __restrict__ wo,
                            const float* __restrict__ fc1, const float* __restrict__ fc2,
                            u16* __restrict__ wT)
{
    int i = blockIdx.x * 256 + threadIdx.x;      // 0 .. 786431
    const float* src; int K, N, off;
    if (i < 262144) {                 // wq, wk, wv, wo: each 256x256
        int m = i >> 16;
        src = (m==0) ? wq : (m==1) ? wk : (m==2) ? wv : wo;
        K = 256; N = 256; off = i & 65535;
    } else if (i < 524288) {          // fc1: K=256 N=1024
        src = fc1; K = 256; N = 1024; off = i - 262144;
    } else {                          // fc2: K=1024 N=256
        src = fc2; K = 1024; N = 256; off = i - 524288;
    }
    int k = off % K, n = off / K;
    wT[i] = f2bf(src[(size_t)k * N + n]);
}

// ---------------- 3x3 depthwise conv + residual (fp32) -----------------------
__global__ __launch_bounds__(256)
void posconv_kernel(const float* __restrict__ x, const float* __restrict__ w,
                    const float* __restrict__ bias, float* __restrict__ out)
{
    int idx = blockIdx.x * 256 + threadIdx.x;    // B*H*W*(C/4)
    int c = (idx & 63) * 4;
    int p = idx >> 6;
    int wp = p & 63, hp = (p >> 6) & 63, bp = p >> 12;
    f4 acc = *reinterpret_cast<const f4*>(bias + c);
    #pragma unroll
    for (int kh = 0; kh < 3; kh++){
        int hh = hp + kh - 1; if ((unsigned)hh >= 64u) continue;
        #pragma unroll
        for (int kw = 0; kw < 3; kw++){
            int ww = wp + kw - 1; if ((unsigned)ww >= 64u) continue;
            f4 xv = *reinterpret_cast<const f4*>(x + (((size_t)(bp*64 + hh))*64 + ww)*256 + c);
            f4 wv = *reinterpret_cast<const f4*>(w + (size_t)(kh*3 + kw)*256 + c);
            acc += xv * wv;
        }
    }
    f4 ctr = *reinterpret_cast<const f4*>(x + (size_t)p*256 + c);
    *reinterpret_cast<f4*>(out + (size_t)p*256 + c) = ctr + acc;
}

// ---------------- 5x5 depthwise conv on bf16 v -> bf16 lepe ------------------
__global__ __launch_bounds__(256)
void lepe_kernel(const u16* __restrict__ v, const float* __restrict__ w,
                 const float* __restrict__ bias, u16* __restrict__ out)
{
    int idx = blockIdx.x * 256 + threadIdx.x;    // Bc*H*W*(C/8)
    int c = (idx & 31) * 8;
    int p = idx >> 5;
    int wp = p & 63, hp = (p >> 6) & 63, bp = p >> 12;
    float acc[8];
    #pragma unroll
    for (int j = 0; j < 8; j++) acc[j] = bias[c + j];
    #pragma unroll
    for (int kh = 0; kh < 5; kh++){
        int hh = hp + kh - 2; if ((unsigned)hh >= 64u) continue;
        #pragma unroll
        for (int kw = 0; kw < 5; kw++){
            int ww = wp + kw - 2; if ((unsigned)ww >= 64u) continue;
            uint4 u = *reinterpret_cast<const uint4*>(v + (((size_t)(bp*64 + hh))*64 + ww)*256 + c);
            float xv[8]; unp8(u, xv);
            const float* wr = w + (size_t)(kh*5 + kw)*256 + c;
            #pragma unroll
            for (int j = 0; j < 8; j++) acc[j] += xv[j] * wr[j];
        }
    }
    uint4 r;
    r.x = pack2(acc[0],acc[1]); r.y = pack2(acc[2],acc[3]);
    r.z = pack2(acc[4],acc[5]); r.w = pack2(acc[6],acc[7]);
    *reinterpret_cast<uint4*>(out + (size_t)p*256 + c) = r;
}

// ---------------- LayerNorm (fp32 in, bf16 out), 4 rows/block (1 per wave) ---
__global__ __launch_bounds__(256)
void ln_kernel(const float* __restrict__ x, const float* __restrict__ g,
               const float* __restrict__ b, u16* __restrict__ y)
{
    int wid = threadIdx.x >> 6, lane = threadIdx.x & 63;
    size_t row = (size_t)blockIdx.x * 4 + wid;
    f4 v = reinterpret_cast<const f4*>(x + row*256)[lane];
    float s  = v.x + v.y + v.z + v.w;
    float q2 = v.x*v.x + v.y*v.y + v.z*v.z + v.w*v.w;
    #pragma unroll
    for (int off = 32; off > 0; off >>= 1){
        s  += __shfl_xor(s,  off);
        q2 += __shfl_xor(q2, off);
    }
    float mean = s * (1.f/256.f);
    float var  = q2 * (1.f/256.f) - mean*mean;
    float rs   = rsqrtf(var + 1e-6f);
    f4 gv = reinterpret_cast<const f4*>(g)[lane];
    f4 bv = reinterpret_cast<const f4*>(b)[lane];
    f4 t = (v - mean) * rs;
    t = t * gv + bv;
    uint2 r;
    r.x = pack2(t.x, t.y); r.y = pack2(t.z, t.w);
    *reinterpret_cast<uint2*>(y + row*256 + (size_t)lane*4) = r;
}

// ---------------- GEMM: out[M,N] = A[M,K](bf16) @ Bt[N,K]^T(bf16) + bias -----
// EPI: 0=store bf16, 1=store bf16*scale, 2=gelu->bf16, 3=+resid -> fp32
// ADD2: A-operand is A + A2 (element-wise, staged during LDS load)
template<int EPI, bool ADD2>
__global__ __launch_bounds__(256)
void gemm_kernel(const u16* __restrict__ A, const u16* __restrict__ A2,
                 const u16* __restrict__ Bt,
                 const float* __restrict__ bias, const float* __restrict__ resid,
                 void* __restrict__ outp, int M, int N, int K, float scale)
{
    __shared__ u16 As[64][32];
    __shared__ u16 Bs[64][32];
    int m0 = blockIdx.x * 64, n0 = blockIdx.y * 64;
    int tid = threadIdx.x, wid = tid >> 6, lane = tid & 63;
    int lr = tid >> 2, lk = (tid & 3) * 8;
    f32x4 acc[4] = {};
    const u16* Ar = A  + (size_t)(m0 + lr) * K + lk;
    const u16* Br = Bt + (size_t)(n0 + lr) * K + lk;
    const u16* A2r = ADD2 ? (A2 + (size_t)(m0 + lr) * K + lk) : nullptr;
    for (int k0 = 0; k0 < K; k0 += 32){
        uint4 ua = *reinterpret_cast<const uint4*>(Ar + k0);
        if constexpr (ADD2){
            uint4 ub = *reinterpret_cast<const uint4*>(A2r + k0);
            float fa[8], fb[8]; unp8(ua, fa); unp8(ub, fb);
            ua.x = pack2(fa[0]+fb[0], fa[1]+fb[1]);
            ua.y = pack2(fa[2]+fb[2], fa[3]+fb[3]);
            ua.z = pack2(fa[4]+fb[4], fa[5]+fb[5]);
            ua.w = pack2(fa[6]+fb[6], fa[7]+fb[7]);
        }
        *reinterpret_cast<uint4*>(&As[lr][lk]) = ua;
        *reinterpret_cast<uint4*>(&Bs[lr][lk]) = *reinterpret_cast<const uint4*>(Br + k0);
        __syncthreads();
        bf16x8 av = *reinterpret_cast<const bf16x8*>(&As[wid*16 + (lane & 15)][(lane >> 4) * 8]);
        #pragma unroll
        for (int nt = 0; nt < 4; nt++){
            bf16x8 bv = *reinterpret_cast<const bf16x8*>(&Bs[nt*16 + (lane & 15)][(lane >> 4) * 8]);
            acc[nt] = __builtin_amdgcn_mfma_f32_16x16x32_bf16(av, bv, acc[nt], 0, 0, 0);
        }
        __syncthreads();
    }
    #pragma unroll
    for (int nt = 0; nt < 4; nt++){
        int col = n0 + nt*16 + (lane & 15);
        float bc = bias[col];
        #pragma unroll
        for (int r = 0; r < 4; r++){
            int row = m0 + wid*16 + ((lane >> 4) << 2) + r;
            float val = acc[nt][r] + bc;
            if constexpr (EPI == 1) val *= scale;
            if constexpr (EPI == 2) val = 0.5f * val * (1.f + erff(val * 0.70710678118654752f));
            if constexpr (EPI == 3){
                size_t o = (size_t)row * N + col;
                reinterpret_cast<float*>(outp)[o] = val + resid[o];
            } else {
                reinterpret_cast<u16*>(outp)[(size_t)row * N + col] = f2bf(val);
            }
        }
    }
}

// ======== 8-wave axial attention.  Block = one (b,line); wave = one head. ====
// LDS head-slab stride 65*33 f32 (== 1 mod 32) -> staging writes spread all
// 32 banks; compute reads are wave-uniform broadcasts (conflict-free).
// In-place safe (vo == v): all v reads staged to LDS before first write.

__global__ __launch_bounds__(512, 2)
void attn_w_kernel(const u16* __restrict__ q, const u16* __restrict__ k,
                   const u16* __restrict__ v, const float* __restrict__ mask,
                   u16* __restrict__ vo)
{
    __shared__ float kl[8][65][33];
    __shared__ float vl[8][65][33];
    int tid = threadIdx.x;
    int hd = tid >> 6, lane = tid & 63;
    size_t base = (size_t)blockIdx.x * 16384;        // (b*64+h) line; rows contiguous
    #pragma unroll
    for (int i = 0; i < 4; i++){
        int e = (i*512 + tid) * 8;
        int row = e >> 8, col = e & 255;
        int h2 = col >> 5, c2 = col & 31;
        float tmp[8];
        uint4 uk = *reinterpret_cast<const uint4*>(k + base + row*256 + col);
        unp8(uk, tmp);
        #pragma unroll
        for (int j = 0; j < 8; j++) kl[h2][row][c2+j] = tmp[j];
        uint4 uv = *reinterpret_cast<const uint4*>(v + base + row*256 + col);
        unp8(uv, tmp);
        #pragma unroll
        for (int j = 0; j < 8; j++) vl[h2][row][c2+j] = tmp[j];
    }
    float qr[32];
    {
        const uint4* qp = reinterpret_cast<const uint4*>(q + base + lane*256 + hd*32);
        #pragma unroll
        for (int j = 0; j < 4; j++) unp8(qp[j], &qr[j*8]);
    }
    __syncthreads();
    const float* mrow = mask + ((size_t)hd * 64 + lane) * 64;
    float s[64];
    #pragma unroll
    for (int kk = 0; kk < 64; kk++){
        float a = 0.f;
        #pragma unroll
        for (int dd = 0; dd < 32; dd++) a += qr[dd] * kl[hd][kk][dd];
        s[kk] = a + mrow[kk];
    }
    float mx = -1e30f;
    #pragma unroll
    for (int kk = 0; kk < 64; kk++) mx = fmaxf(mx, s[kk]);
    float sum = 0.f;
    #pragma unroll
    for (int kk = 0; kk < 64; kk++){ float p = __expf(s[kk] - mx); s[kk] = p; sum += p; }
    float inv = 1.f / sum;
    float o[32];
    #pragma unroll
    for (int dd = 0; dd < 32; dd++) o[dd] = 0.f;
    #pragma unroll
    for (int kk = 0; kk < 64; kk++){
        float p = s[kk];
        #pragma unroll
        for (int dd = 0; dd < 32; dd++) o[dd] += p * vl[hd][kk][dd];
    }
    u32 ow[16];
    #pragma unroll
    for (int j = 0; j < 16; j++) ow[j] = pack2(o[2*j] * inv, o[2*j+1] * inv);
    uint4* op = reinterpret_cast<uint4*>(vo + base + lane*256 + hd*32);
    #pragma unroll
    for (int j = 0; j < 4; j++) op[j] = make_uint4(ow[4*j], ow[4*j+1], ow[4*j+2], ow[4*j+3]);
}

__global__ __launch_bounds__(512, 2)
void attn_h_kernel(const u16* __restrict__ q, const u16* __restrict__ k,
                   const u16* __restrict__ vo, const float* __restrict__ mask,
                   u16* __restrict__ outb)
{
    __shared__ float kl[8][65][33];
    __shared__ float vl[8][65][33];
    int tid = threadIdx.x;
    int hd = tid >> 6, lane = tid & 63;
    int bid = blockIdx.x;                            // b*64 + w
    size_t base = (size_t)(bid >> 6) * 1048576 + (size_t)(bid & 63) * 256;
    const size_t RS = 16384;                         // row stride along H
    #pragma unroll
    for (int i = 0; i < 4; i++){
        int e = (i*512 + tid) * 8;
        int row = e >> 8, col = e & 255;
        int h2 = col >> 5, c2 = col & 31;
        float tmp[8];
        uint4 uk = *reinterpret_cast<const uint4*>(k  + base + (size_t)row * RS + col);
        unp8(uk, tmp);
        #pragma unroll
        for (int j = 0; j < 8; j++) kl[h2][row][c2+j] = tmp[j];
        uint4 uv = *reinterpret_cast<const uint4*>(vo + base + (size_t)row * RS + col);
        unp8(uv, tmp);
        #pragma unroll
        for (int j = 0; j < 8; j++) vl[h2][row][c2+j] = tmp[j];
    }
    float qr[32];
    {
        const uint4* qp = reinterpret_cast<const uint4*>(q + base + (size_t)lane * RS + hd*32);
        #pragma unroll
        for (int j = 0; j < 4; j++) unp8(qp[j], &qr[j*8]);
    }
    __syncthreads();
    const float* mrow = mask + ((size_t)hd * 64 + lane) * 64;
    float s[64];
    #pragma unroll
    for (int kk = 0; kk < 64; kk++){
        float a = 0.f;
        #pragma unroll
        for (int dd = 0; dd < 32; dd++) a += qr[dd] * kl[hd][kk][dd];
        s[kk] = a + mrow[kk];
    }
    float mx = -1e30f;
    #pragma unroll
    for (int kk = 0; kk < 64; kk++) mx = fmaxf(mx, s[kk]);
    float sum = 0.f;
    #pragma unroll
    for (int kk = 0; kk < 64; kk++){ float p = __expf(s[kk] - mx); s[kk] = p; sum += p; }
    float inv = 1.f / sum;
    float o[32];
    #pragma unroll
    for (int dd = 0; dd < 32; dd++) o[dd] = 0.f;
    #pragma unroll
    for (int kk = 0; kk < 64; kk++){
        float p = s[kk];
        #pragma unroll
        for (int dd = 0; dd < 32; dd++) o[dd] += p * vl[hd][kk][dd];
    }
    u32 ow[16];
    #pragma unroll
    for (int j = 0; j < 16; j++) ow[j] = pack2(o[2*j] * inv, o[2*j+1] * inv);
    uint4* op = reinterpret_cast<uint4*>(outb + base + (size_t)lane * RS + hd*32);
    #pragma unroll
    for (int j = 0; j < 4; j++) op[j] = make_uint4(ow[4*j], ow[4*j+1], ow[4*j+2], ow[4*j+3]);
}

extern "C" void kernel_launch(void* const* d_in, const int* in_sizes, int n_in,
                              void* d_out, int out_size, void* d_ws, size_t ws_size,
                              hipStream_t stream)
{
    const float* x      = (const float*)d_in[0];
    const float* mask_h = (const float*)d_in[1];
    const float* mask_w = (const float*)d_in[2];
    const float* pos_w  = (const float*)d_in[3];
    const float* pos_b  = (const float*)d_in[4];
    const float* ln1_g  = (const float*)d_in[5];
    const float* ln1_b  = (const float*)d_in[6];
    const float* wq     = (const float*)d_in[7];
    const float* bq     = (const float*)d_in[8];
    const float* wk     = (const float*)d_in[9];
    const float* bk     = (const float*)d_in[10];
    const float* wv     = (const float*)d_in[11];
    const float* bv     = (const float*)d_in[12];
    const float* lepe_w = (const float*)d_in[13];
    const float* lepe_b = (const float*)d_in[14];
    const float* wo     = (const float*)d_in[15];
    const float* bo     = (const float*)d_in[16];
    const float* ln2_g  = (const float*)d_in[17];
    const float* ln2_b  = (const float*)d_in[18];
    const float* fc1_w  = (const float*)d_in[19];
    const float* fc1_b  = (const float*)d_in[20];
    const float* fc2_w  = (const float*)d_in[21];
    const float* fc2_b  = (const float*)d_in[22];

    const size_t MB = 1u << 20;
    float* x1 = (float*)d_out;   // fp32 residual lives in d_out (element-wise RMW only)

    int Bc = 1;
    for (int c = 16; c >= 1; c >>= 1){
        if (ws_size >= (2 + 10 * (size_t)c) * MB) { Bc = c; break; }
    }

    char* ws = (char*)d_ws;
    u16* wT  = (u16*)ws;                       // 1.5 MiB bf16 transposed weights
    u16* wqT = wT, *wkT = wT + 65536, *wvT = wT + 131072, *woT = wT + 196608;
    u16* fc1T = wT + 262144, *fc2T = wT + 524288;
    size_t cb = (size_t)Bc * 2 * MB;           // bytes per bf16 chunk buffer
    u16* y   = (u16*)(ws + 2*MB);
    u16* qb  = (u16*)(ws + 2*MB + cb);
    u16* kb  = (u16*)(ws + 2*MB + 2*cb);
    u16* vb  = (u16*)(ws + 2*MB + 3*cb);
    u16* lep = (u16*)(ws + 2*MB + 4*cb);
    u16* hb  = qb;                             // MLP hidden overlays q,k,v,lep

    dim3 blk(256);
    convert_weights_kernel<<<3072, blk, 0, stream>>>(wq, wk, wv, wo, fc1_w, fc2_w, wT);
    posconv_kernel<<<16384, blk, 0, stream>>>(x, pos_w, pos_b, x1);

    const int nchunk = 16 / Bc;
    const int R = Bc * 4096;                   // rows per chunk
    for (int c = 0; c < nchunk; c++){
        float* xc = x1 + (size_t)c * R * 256;
        dim3 gq(R/64, 4), gf(R/64, 16);
        ln_kernel<<<R/4, blk, 0, stream>>>(xc, ln1_g, ln1_b, y);
        gemm_kernel<0,false><<<gq, blk, 0, stream>>>(y, nullptr, wqT, bq, nullptr, qb, R, 256, 256, 1.f);
        gemm_kernel<1,false><<<gq, blk, 0, stream>>>(y, nullptr, wkT, bk, nullptr, kb, R, 256, 256, 0.17677669529663687f);
        gemm_kernel<0,false><<<gq, blk, 0, stream>>>(y, nullptr, wvT, bv, nullptr, vb, R, 256, 256, 1.f);
        lepe_kernel<<<Bc*512, blk, 0, stream>>>(vb, lepe_w, lepe_b, lep);
        attn_w_kernel<<<Bc*64, 512, 0, stream>>>(qb, kb, vb, mask_w, vb);    // vo in-place
        attn_h_kernel<<<Bc*64, 512, 0, stream>>>(qb, kb, vb, mask_h, vb);    // attn in-place
        // x2 = x1 + (attn + lepe) @ wo + bo   (lepe folded into A-staging)
        gemm_kernel<3,true><<<gq, blk, 0, stream>>>(vb, lep, woT, bo, xc, (void*)xc, R, 256, 256, 1.f);
        ln_kernel<<<R/4, blk, 0, stream>>>(xc, ln2_g, ln2_b, y);
        gemm_kernel<2,false><<<gf, blk, 0, stream>>>(y, nullptr, fc1T, fc1_b, nullptr, hb, R, 1024, 256, 1.f);
        gemm_kernel<3,false><<<gq, blk, 0, stream>>>(hb, nullptr, fc2T, fc2_b, xc, (void*)xc, R, 256, 1024, 1.f);
    }
}

// Round 4
// 725.262 us; speedup vs baseline: 1.4329x; 1.3654x over previous
//
#include <hip/hip_runtime.h>
#include <hip/hip_bf16.h>
#include <math.h>

typedef unsigned short u16;
typedef unsigned int   u32;
typedef float f4   __attribute__((ext_vector_type(4)));
typedef float f32x4 __attribute__((ext_vector_type(4)));
typedef __bf16 bf16x8 __attribute__((ext_vector_type(8)));

#define BDIM 16
#define HDIM 64
#define WDIM 64
#define CDIM 256
#define NHEAD 8
#define DHEAD 32
#define FDIM 1024
#define MROWS (BDIM*HDIM*WDIM)   // 65536

__device__ inline float blo(u32 u){ return __uint_as_float(u << 16); }
__device__ inline float bhi(u32 u){ return __uint_as_float(u & 0xffff0000u); }

__device__ inline u16 f2bf(float f){
    __bf16 h = (__bf16)f;
    return __builtin_bit_cast(unsigned short, h);
}
__device__ inline __bf16 u2b(u16 x){ return __builtin_bit_cast(__bf16, x); }
__device__ inline u32 pack2(float lo, float hi){
    return (u32)f2bf(lo) | ((u32)f2bf(hi) << 16);
}
__device__ inline void unp8(uint4 u, float* d){
    d[0]=blo(u.x); d[1]=bhi(u.x); d[2]=blo(u.y); d[3]=bhi(u.y);
    d[4]=blo(u.z); d[5]=bhi(u.z); d[6]=blo(u.w); d[7]=bhi(u.w);
}

// ---------------- weight convert + transpose: dst[n*K+k] = bf16(src[k*N+n]) ---
__global__ __launch_bounds__(256)
void convert_weights_kernel(const float* __restrict__ wq, const float* __restrict__ wk,
                            const float* __restrict__ wv, const float* __restrict__ wo,
                            const float* __restrict__ fc1, const float* __restrict__ fc2,
                            u16* __restrict__ wT)
{
    int i = blockIdx.x * 256 + threadIdx.x;      // 0 .. 786431
    const float* src; int K, N, off;
    if (i < 262144) {                 // wq, wk, wv, wo: each 256x256
        int m = i >> 16;
        src = (m==0) ? wq : (m==1) ? wk : (m==2) ? wv : wo;
        K = 256; N = 256; off = i & 65535;
    } else if (i < 524288) {          // fc1: K=256 N=1024
        src = fc1; K = 256; N = 1024; off = i - 262144;
    } else {                          // fc2: K=1024 N=256
        src = fc2; K = 1024; N = 256; off = i - 524288;
    }
    int k = off % K, n = off / K;
    wT[i] = f2bf(src[(size_t)k * N + n]);
}

// ---------------- 3x3 depthwise conv + residual (fp32) -----------------------
__global__ __launch_bounds__(256)
void posconv_kernel(const float* __restrict__ x, const float* __restrict__ w,
                    const float* __restrict__ bias, float* __restrict__ out)
{
    int idx = blockIdx.x * 256 + threadIdx.x;    // B*H*W*(C/4)
    int c = (idx & 63) * 4;
    int p = idx >> 6;
    int wp = p & 63, hp = (p >> 6) & 63, bp = p >> 12;
    f4 acc = *reinterpret_cast<const f4*>(bias + c);
    #pragma unroll
    for (int kh = 0; kh < 3; kh++){
        int hh = hp + kh - 1; if ((unsigned)hh >= 64u) continue;
        #pragma unroll
        for (int kw = 0; kw < 3; kw++){
            int ww = wp + kw - 1; if ((unsigned)ww >= 64u) continue;
            f4 xv = *reinterpret_cast<const f4*>(x + (((size_t)(bp*64 + hh))*64 + ww)*256 + c);
            f4 wv = *reinterpret_cast<const f4*>(w + (size_t)(kh*3 + kw)*256 + c);
            acc += xv * wv;
        }
    }
    f4 ctr = *reinterpret_cast<const f4*>(x + (size_t)p*256 + c);
    *reinterpret_cast<f4*>(out + (size_t)p*256 + c) = ctr + acc;
}

// ---------------- 5x5 depthwise conv on bf16 v -> bf16 lepe ------------------
__global__ __launch_bounds__(256)
void lepe_kernel(const u16* __restrict__ v, const float* __restrict__ w,
                 const float* __restrict__ bias, u16* __restrict__ out)
{
    int idx = blockIdx.x * 256 + threadIdx.x;    // Bc*H*W*(C/8)
    int c = (idx & 31) * 8;
    int p = idx >> 5;
    int wp = p & 63, hp = (p >> 6) & 63, bp = p >> 12;
    float acc[8];
    #pragma unroll
    for (int j = 0; j < 8; j++) acc[j] = bias[c + j];
    #pragma unroll
    for (int kh = 0; kh < 5; kh++){
        int hh = hp + kh - 2; if ((unsigned)hh >= 64u) continue;
        #pragma unroll
        for (int kw = 0; kw < 5; kw++){
            int ww = wp + kw - 2; if ((unsigned)ww >= 64u) continue;
            uint4 u = *reinterpret_cast<const uint4*>(v + (((size_t)(bp*64 + hh))*64 + ww)*256 + c);
            float xv[8]; unp8(u, xv);
            const float* wr = w + (size_t)(kh*5 + kw)*256 + c;
            #pragma unroll
            for (int j = 0; j < 8; j++) acc[j] += xv[j] * wr[j];
        }
    }
    uint4 r;
    r.x = pack2(acc[0],acc[1]); r.y = pack2(acc[2],acc[3]);
    r.z = pack2(acc[4],acc[5]); r.w = pack2(acc[6],acc[7]);
    *reinterpret_cast<uint4*>(out + (size_t)p*256 + c) = r;
}

// ---------------- LayerNorm (fp32 in, bf16 out), 4 rows/block (1 per wave) ---
__global__ __launch_bounds__(256)
void ln_kernel(const float* __restrict__ x, const float* __restrict__ g,
               const float* __restrict__ b, u16* __restrict__ y)
{
    int wid = threadIdx.x >> 6, lane = threadIdx.x & 63;
    size_t row = (size_t)blockIdx.x * 4 + wid;
    f4 v = reinterpret_cast<const f4*>(x + row*256)[lane];
    float s  = v.x + v.y + v.z + v.w;
    float q2 = v.x*v.x + v.y*v.y + v.z*v.z + v.w*v.w;
    #pragma unroll
    for (int off = 32; off > 0; off >>= 1){
        s  += __shfl_xor(s,  off);
        q2 += __shfl_xor(q2, off);
    }
    float mean = s * (1.f/256.f);
    float var  = q2 * (1.f/256.f) - mean*mean;
    float rs   = rsqrtf(var + 1e-6f);
    f4 gv = reinterpret_cast<const f4*>(g)[lane];
    f4 bv = reinterpret_cast<const f4*>(b)[lane];
    f4 t = (v - mean) * rs;
    t = t * gv + bv;
    uint2 r;
    r.x = pack2(t.x, t.y); r.y = pack2(t.z, t.w);
    *reinterpret_cast<uint2*>(y + row*256 + (size_t)lane*4) = r;
}

// ---------------- GEMM: out[M,N] = A[M,K](bf16) @ Bt[N,K]^T(bf16) + bias -----
// EPI: 0=store bf16, 1=store bf16*scale, 2=gelu->bf16, 3=+resid -> fp32
// ADD2: A-operand is A + A2 (element-wise, staged during LDS load)
template<int EPI, bool ADD2>
__global__ __launch_bounds__(256)
void gemm_kernel(const u16* __restrict__ A, const u16* __restrict__ A2,
                 const u16* __restrict__ Bt,
                 const float* __restrict__ bias, const float* __restrict__ resid,
                 void* __restrict__ outp, int M, int N, int K, float scale)
{
    __shared__ u16 As[64][32];
    __shared__ u16 Bs[64][32];
    int m0 = blockIdx.x * 64, n0 = blockIdx.y * 64;
    int tid = threadIdx.x, wid = tid >> 6, lane = tid & 63;
    int lr = tid >> 2, lk = (tid & 3) * 8;
    f32x4 acc[4] = {};
    const u16* Ar = A  + (size_t)(m0 + lr) * K + lk;
    const u16* Br = Bt + (size_t)(n0 + lr) * K + lk;
    const u16* A2r = ADD2 ? (A2 + (size_t)(m0 + lr) * K + lk) : nullptr;
    for (int k0 = 0; k0 < K; k0 += 32){
        uint4 ua = *reinterpret_cast<const uint4*>(Ar + k0);
        if constexpr (ADD2){
            uint4 ub = *reinterpret_cast<const uint4*>(A2r + k0);
            float fa[8], fb[8]; unp8(ua, fa); unp8(ub, fb);
            ua.x = pack2(fa[0]+fb[0], fa[1]+fb[1]);
            ua.y = pack2(fa[2]+fb[2], fa[3]+fb[3]);
            ua.z = pack2(fa[4]+fb[4], fa[5]+fb[5]);
            ua.w = pack2(fa[6]+fb[6], fa[7]+fb[7]);
        }
        *reinterpret_cast<uint4*>(&As[lr][lk]) = ua;
        *reinterpret_cast<uint4*>(&Bs[lr][lk]) = *reinterpret_cast<const uint4*>(Br + k0);
        __syncthreads();
        bf16x8 av = *reinterpret_cast<const bf16x8*>(&As[wid*16 + (lane & 15)][(lane >> 4) * 8]);
        #pragma unroll
        for (int nt = 0; nt < 4; nt++){
            bf16x8 bv = *reinterpret_cast<const bf16x8*>(&Bs[nt*16 + (lane & 15)][(lane >> 4) * 8]);
            acc[nt] = __builtin_amdgcn_mfma_f32_16x16x32_bf16(av, bv, acc[nt], 0, 0, 0);
        }
        __syncthreads();
    }
    #pragma unroll
    for (int nt = 0; nt < 4; nt++){
        int col = n0 + nt*16 + (lane & 15);
        float bc = bias[col];
        #pragma unroll
        for (int r = 0; r < 4; r++){
            int row = m0 + wid*16 + ((lane >> 4) << 2) + r;
            float val = acc[nt][r] + bc;
            if constexpr (EPI == 1) val *= scale;
            if constexpr (EPI == 2) val = 0.5f * val * (1.f + erff(val * 0.70710678118654752f));
            if constexpr (EPI == 3){
                size_t o = (size_t)row * N + col;
                reinterpret_cast<float*>(outp)[o] = val + resid[o];
            } else {
                reinterpret_cast<u16*>(outp)[(size_t)row * N + col] = f2bf(val);
            }
        }
    }
}

// ======== MFMA axial attention. Block = one (b,line); wave = one head. =======
// S^T = mfma(A=K, B=Q): lane holds S[q=tj*16+lm][kk=ti*16+g*4+r]
//   -> softmax over kk = in-lane reduce + shfl_xor(16,32); mask loads are f4.
// P (with 1/sum folded) -> LDS -> standard A-frags for PV = mfma(P, V).
// O returns via LDS (reusing P slab) for coalesced 16B global stores.
// In-place safe (out == v): all v reads staged to LDS before any write.
template<bool HAXIS>
__global__ __launch_bounds__(512, 2)
void attn_mfma_kernel(const u16* __restrict__ q, const u16* __restrict__ k,
                      const u16* __restrict__ v, const float* __restrict__ mask,
                      u16* __restrict__ out)
{
    __shared__ u16 Kl[8][64][40];   // pad 8: b128 frag reads balanced
    __shared__ u16 Vl[8][64][34];   // pad 2: u16 transpose reads conflict-free
    __shared__ u16 Pl[8][64][72];   // P; later reused as O_lds[8][64][40]
    u16* Ol = &Pl[0][0][0];

    const int tid = threadIdx.x;
    const int lane = tid & 63, wv = tid >> 6;     // wv = head
    const int g = lane >> 4, lm = lane & 15;

    size_t base, RS;
    if constexpr (HAXIS){
        base = (size_t)(blockIdx.x >> 6) * 1048576 + (size_t)(blockIdx.x & 63) * 256;
        RS = 16384;
    } else {
        base = (size_t)blockIdx.x * 16384;
        RS = 256;
    }

    // ---- stage K and V (bf16, coalesced 16B) ----
    #pragma unroll
    for (int rnd = 0; rnd < 4; rnd++){
        int c = rnd*512 + tid;                    // (kk, hd, dhalf)
        int kk = c >> 5, hd = (c >> 2) & 7, dh = c & 3;
        size_t gco = base + (size_t)kk*RS + hd*32 + dh*8;
        uint4 uk = *reinterpret_cast<const uint4*>(k + gco);
        *reinterpret_cast<uint4*>(&Kl[hd][kk][dh*8]) = uk;
        uint4 uv = *reinterpret_cast<const uint4*>(v + gco);
        *reinterpret_cast<uint4*>(&Vl[hd][kk][dh*8]) = uv;
    }
    // ---- Q fragments direct from global (B-operand: col=q, k=d) ----
    bf16x8 qf[4];
    #pragma unroll
    for (int tj = 0; tj < 4; tj++)
        qf[tj] = *reinterpret_cast<const bf16x8*>(q + base + (size_t)(tj*16+lm)*RS + wv*32 + g*8);
    __syncthreads();

    // ---- S^T = K·Q^T : 4(kk-tiles) x 4(q-tiles), K=32 ----
    f32x4 st[4][4];                               // [ti=kk][tj=q]
    #pragma unroll
    for (int ti = 0; ti < 4; ti++){
        bf16x8 kf = *reinterpret_cast<const bf16x8*>(&Kl[wv][ti*16+lm][g*8]);
        #pragma unroll
        for (int tj = 0; tj < 4; tj++){
            f32x4 z = {};
            st[ti][tj] = __builtin_amdgcn_mfma_f32_16x16x32_bf16(kf, qf[tj], z, 0, 0, 0);
        }
    }
    // ---- + mask (f4 loads: kk is the register axis) ----
    #pragma unroll
    for (int tj = 0; tj < 4; tj++){
        const float* mrow = mask + ((size_t)wv*64 + tj*16+lm)*64;
        #pragma unroll
        for (int ti = 0; ti < 4; ti++)
            st[ti][tj] += *reinterpret_cast<const f4*>(mrow + ti*16 + g*4);
    }
    // ---- softmax over kk, fold 1/sum, write P(bf16) to LDS ----
    #pragma unroll
    for (int tj = 0; tj < 4; tj++){
        float mx = -1e30f;
        #pragma unroll
        for (int ti = 0; ti < 4; ti++)
            #pragma unroll
            for (int r = 0; r < 4; r++) mx = fmaxf(mx, st[ti][tj][r]);
        mx = fmaxf(mx, __shfl_xor(mx, 16));
        mx = fmaxf(mx, __shfl_xor(mx, 32));
        float sum = 0.f;
        #pragma unroll
        for (int ti = 0; ti < 4; ti++)
            #pragma unroll
            for (int r = 0; r < 4; r++){
                float p = __expf(st[ti][tj][r] - mx);
                st[ti][tj][r] = p; sum += p;
            }
        sum += __shfl_xor(sum, 16);
        sum += __shfl_xor(sum, 32);
        float inv = 1.f / sum;
        #pragma unroll
        for (int ti = 0; ti < 4; ti++){
            uint2 pw;
            pw.x = pack2(st[ti][tj][0]*inv, st[ti][tj][1]*inv);
            pw.y = pack2(st[ti][tj][2]*inv, st[ti][tj][3]*inv);
            *reinterpret_cast<uint2*>(&Pl[wv][tj*16+lm][ti*16+g*4]) = pw;
        }
    }
    // ---- PV: O[q][d] = sum_kk P[q][kk] V[kk][d] ----
    f32x4 oc[4][2] = {};                          // [q-tile][d-tile]
    #pragma unroll
    for (int kb = 0; kb < 2; kb++){
        bf16x8 vf[2];
        #pragma unroll
        for (int dt = 0; dt < 2; dt++)
            #pragma unroll
            for (int j = 0; j < 8; j++)
                vf[dt][j] = u2b(Vl[wv][kb*32 + g*8 + j][dt*16 + lm]);
        #pragma unroll
        for (int ti2 = 0; ti2 < 4; ti2++){
            bf16x8 pf = *reinterpret_cast<const bf16x8*>(&Pl[wv][ti2*16+lm][kb*32 + g*8]);
            oc[ti2][0] = __builtin_amdgcn_mfma_f32_16x16x32_bf16(pf, vf[0], oc[ti2][0], 0, 0, 0);
            oc[ti2][1] = __builtin_amdgcn_mfma_f32_16x16x32_bf16(pf, vf[1], oc[ti2][1], 0, 0, 0);
        }
    }
    __syncthreads();   // all P reads done before O overwrites the P slab
    #pragma unroll
    for (int ti2 = 0; ti2 < 4; ti2++)
        #pragma unroll
        for (int dt = 0; dt < 2; dt++)
            #pragma unroll
            for (int r = 0; r < 4; r++)
                Ol[((size_t)wv*64 + ti2*16 + g*4 + r)*40 + dt*16 + lm] = f2bf(oc[ti2][dt][r]);
    __syncthreads();
    // ---- coalesced global write ----
    #pragma unroll
    for (int rnd = 0; rnd < 4; rnd++){
        int c = rnd*512 + tid;
        int row = c >> 5, hd = (c >> 2) & 7, dh = c & 3;
        uint4 u = *reinterpret_cast<const uint4*>(&Ol[((size_t)hd*64 + row)*40 + dh*8]);
        *reinterpret_cast<uint4*>(out + base + (size_t)row*RS + hd*32 + dh*8) = u;
    }
}

extern "C" void kernel_launch(void* const* d_in, const int* in_sizes, int n_in,
                              void* d_out, int out_size, void* d_ws, size_t ws_size,
                              hipStream_t stream)
{
    const float* x      = (const float*)d_in[0];
    const float* mask_h = (const float*)d_in[1];
    const float* mask_w = (const float*)d_in[2];
    const float* pos_w  = (const float*)d_in[3];
    const float* pos_b  = (const float*)d_in[4];
    const float* ln1_g  = (const float*)d_in[5];
    const float* ln1_b  = (const float*)d_in[6];
    const float* wq     = (const float*)d_in[7];
    const float* bq     = (const float*)d_in[8];
    const float* wk     = (const float*)d_in[9];
    const float* bk     = (const float*)d_in[10];
    const float* wv     = (const float*)d_in[11];
    const float* bv     = (const float*)d_in[12];
    const float* lepe_w = (const float*)d_in[13];
    const float* lepe_b = (const float*)d_in[14];
    const float* wo     = (const float*)d_in[15];
    const float* bo     = (const float*)d_in[16];
    const float* ln2_g  = (const float*)d_in[17];
    const float* ln2_b  = (const float*)d_in[18];
    const float* fc1_w  = (const float*)d_in[19];
    const float* fc1_b  = (const float*)d_in[20];
    const float* fc2_w  = (const float*)d_in[21];
    const float* fc2_b  = (const float*)d_in[22];

    const size_t MB = 1u << 20;
    float* x1 = (float*)d_out;   // fp32 residual lives in d_out (element-wise RMW only)

    int Bc = 1;
    for (int c = 16; c >= 1; c >>= 1){
        if (ws_size >= (2 + 10 * (size_t)c) * MB) { Bc = c; break; }
    }

    char* ws = (char*)d_ws;
    u16* wT  = (u16*)ws;                       // 1.5 MiB bf16 transposed weights
    u16* wqT = wT, *wkT = wT + 65536, *wvT = wT + 131072, *woT = wT + 196608;
    u16* fc1T = wT + 262144, *fc2T = wT + 524288;
    size_t cb = (size_t)Bc * 2 * MB;           // bytes per bf16 chunk buffer
    u16* y   = (u16*)(ws + 2*MB);
    u16* qb  = (u16*)(ws + 2*MB + cb);
    u16* kb  = (u16*)(ws + 2*MB + 2*cb);
    u16* vb  = (u16*)(ws + 2*MB + 3*cb);
    u16* lep = (u16*)(ws + 2*MB + 4*cb);
    u16* hb  = qb;                             // MLP hidden overlays q,k,v,lep

    dim3 blk(256);
    convert_weights_kernel<<<3072, blk, 0, stream>>>(wq, wk, wv, wo, fc1_w, fc2_w, wT);
    posconv_kernel<<<16384, blk, 0, stream>>>(x, pos_w, pos_b, x1);

    const int nchunk = 16 / Bc;
    const int R = Bc * 4096;                   // rows per chunk
    for (int c = 0; c < nchunk; c++){
        float* xc = x1 + (size_t)c * R * 256;
        dim3 gq(R/64, 4), gf(R/64, 16);
        ln_kernel<<<R/4, blk, 0, stream>>>(xc, ln1_g, ln1_b, y);
        gemm_kernel<0,false><<<gq, blk, 0, stream>>>(y, nullptr, wqT, bq, nullptr, qb, R, 256, 256, 1.f);
        gemm_kernel<1,false><<<gq, blk, 0, stream>>>(y, nullptr, wkT, bk, nullptr, kb, R, 256, 256, 0.17677669529663687f);
        gemm_kernel<0,false><<<gq, blk, 0, stream>>>(y, nullptr, wvT, bv, nullptr, vb, R, 256, 256, 1.f);
        lepe_kernel<<<Bc*512, blk, 0, stream>>>(vb, lepe_w, lepe_b, lep);
        attn_mfma_kernel<false><<<Bc*64, 512, 0, stream>>>(qb, kb, vb, mask_w, vb); // vo in-place
        attn_mfma_kernel<true ><<<Bc*64, 512, 0, stream>>>(qb, kb, vb, mask_h, vb); // attn in-place
        // x2 = x1 + (attn + lepe) @ wo + bo   (lepe folded into A-staging)
        gemm_kernel<3,true><<<gq, blk, 0, stream>>>(vb, lep, woT, bo, xc, (void*)xc, R, 256, 256, 1.f);
        ln_kernel<<<R/4, blk, 0, stream>>>(xc, ln2_g, ln2_b, y);
        gemm_kernel<2,false><<<gf, blk, 0, stream>>>(y, nullptr, fc1T, fc1_b, nullptr, hb, R, 1024, 256, 1.f);
        gemm_kernel<3,false><<<gq, blk, 0, stream>>>(hb, nullptr, fc2T, fc2_b, xc, (void*)xc, R, 256, 1024, 1.f);
    }
}

// Round 7
// 665.998 us; speedup vs baseline: 1.5604x; 1.0890x over previous
//
#include <hip/hip_runtime.h>
#include <hip/hip_bf16.h>
#include <math.h>

typedef unsigned short u16;
typedef unsigned int   u32;
typedef float f4   __attribute__((ext_vector_type(4)));
typedef float f32x4 __attribute__((ext_vector_type(4)));
typedef __bf16 bf16x8 __attribute__((ext_vector_type(8)));

#define BDIM 16
#define HDIM 64
#define WDIM 64
#define CDIM 256
#define NHEAD 8
#define DHEAD 32
#define FDIM 1024
#define MROWS (BDIM*HDIM*WDIM)   // 65536

__device__ inline float blo(u32 u){ return __uint_as_float(u << 16); }
__device__ inline float bhi(u32 u){ return __uint_as_float(u & 0xffff0000u); }

__device__ inline u16 f2bf(float f){
    __bf16 h = (__bf16)f;
    return __builtin_bit_cast(unsigned short, h);
}
__device__ inline __bf16 u2b(u16 x){ return __builtin_bit_cast(__bf16, x); }
__device__ inline u32 pack2(float lo, float hi){
    return (u32)f2bf(lo) | ((u32)f2bf(hi) << 16);
}
__device__ inline void unp8(uint4 u, float* d){
    d[0]=blo(u.x); d[1]=bhi(u.x); d[2]=blo(u.y); d[3]=bhi(u.y);
    d[4]=blo(u.z); d[5]=bhi(u.z); d[6]=blo(u.w); d[7]=bhi(u.w);
}
// async global->LDS, 16B per lane; LDS dest is wave-uniform base + lane*16
__device__ inline void gld16(const void* g, void* l){
    __builtin_amdgcn_global_load_lds(
        (const __attribute__((address_space(1))) void*)g,
        (__attribute__((address_space(3))) void*)l, 16, 0, 0);
}

// ---------------- weight convert + transpose: dst[n*K+k] = bf16(src[k*N+n]) ---
__global__ __launch_bounds__(256)
void convert_weights_kernel(const float* __restrict__ wq, const float* __restrict__ wk,
                            const float* __restrict__ wv, const float* __restrict__ wo,
                            const float* __restrict__ fc1, const float* __restrict__ fc2,
                            u16* __restrict__ wT)
{
    int i = blockIdx.x * 256 + threadIdx.x;      // 0 .. 786431
    const float* src; int K, N, off;
    if (i < 262144) {                 // wq, wk, wv, wo: each 256x256
        int m = i >> 16;
        src = (m==0) ? wq : (m==1) ? wk : (m==2) ? wv : wo;
        K = 256; N = 256; off = i & 65535;
    } else if (i < 524288) {          // fc1: K=256 N=1024
        src = fc1; K = 256; N = 1024; off = i - 262144;
    } else {                          // fc2: K=1024 N=256
        src = fc2; K = 1024; N = 256; off = i - 524288;
    }
    int k = off % K, n = off / K;
    wT[i] = f2bf(src[(size_t)k * N + n]);
}

// ---------------- 3x3 depthwise conv + residual (fp32) -----------------------
__global__ __launch_bounds__(256)
void posconv_kernel(const float* __restrict__ x, const float* __restrict__ w,
                    const float* __restrict__ bias, float* __restrict__ out)
{
    int idx = blockIdx.x * 256 + threadIdx.x;    // B*H*W*(C/4)
    int c = (idx & 63) * 4;
    int p = idx >> 6;
    int wp = p & 63, hp = (p >> 6) & 63, bp = p >> 12;
    f4 acc = *reinterpret_cast<const f4*>(bias + c);
    #pragma unroll
    for (int kh = 0; kh < 3; kh++){
        int hh = hp + kh - 1; if ((unsigned)hh >= 64u) continue;
        #pragma unroll
        for (int kw = 0; kw < 3; kw++){
            int ww = wp + kw - 1; if ((unsigned)ww >= 64u) continue;
            f4 xv = *reinterpret_cast<const f4*>(x + (((size_t)(bp*64 + hh))*64 + ww)*256 + c);
            f4 wv = *reinterpret_cast<const f4*>(w + (size_t)(kh*3 + kw)*256 + c);
            acc += xv * wv;
        }
    }
    f4 ctr = *reinterpret_cast<const f4*>(x + (size_t)p*256 + c);
    *reinterpret_cast<f4*>(out + (size_t)p*256 + c) = ctr + acc;
}

// ---------------- 5x5 depthwise conv on bf16 v -> bf16 lepe ------------------
__global__ __launch_bounds__(256)
void lepe_kernel(const u16* __restrict__ v, const float* __restrict__ w,
                 const float* __restrict__ bias, u16* __restrict__ out)
{
    int idx = blockIdx.x * 256 + threadIdx.x;    // Bc*H*W*(C/8)
    int c = (idx & 31) * 8;
    int p = idx >> 5;
    int wp = p & 63, hp = (p >> 6) & 63, bp = p >> 12;
    float acc[8];
    #pragma unroll
    for (int j = 0; j < 8; j++) acc[j] = bias[c + j];
    #pragma unroll
    for (int kh = 0; kh < 5; kh++){
        int hh = hp + kh - 2; if ((unsigned)hh >= 64u) continue;
        #pragma unroll
        for (int kw = 0; kw < 5; kw++){
            int ww = wp + kw - 2; if ((unsigned)ww >= 64u) continue;
            uint4 u = *reinterpret_cast<const uint4*>(v + (((size_t)(bp*64 + hh))*64 + ww)*256 + c);
            float xv[8]; unp8(u, xv);
            const float* wr = w + (size_t)(kh*5 + kw)*256 + c;
            #pragma unroll
            for (int j = 0; j < 8; j++) acc[j] += xv[j] * wr[j];
        }
    }
    uint4 r;
    r.x = pack2(acc[0],acc[1]); r.y = pack2(acc[2],acc[3]);
    r.z = pack2(acc[4],acc[5]); r.w = pack2(acc[6],acc[7]);
    *reinterpret_cast<uint4*>(out + (size_t)p*256 + c) = r;
}

// ---------------- LayerNorm (fp32 in, bf16 out), 4 rows/block (1 per wave) ---
__global__ __launch_bounds__(256)
void ln_kernel(const float* __restrict__ x, const float* __restrict__ g,
               const float* __restrict__ b, u16* __restrict__ y)
{
    int wid = threadIdx.x >> 6, lane = threadIdx.x & 63;
    size_t row = (size_t)blockIdx.x * 4 + wid;
    f4 v = reinterpret_cast<const f4*>(x + row*256)[lane];
    float s  = v.x + v.y + v.z + v.w;
    float q2 = v.x*v.x + v.y*v.y + v.z*v.z + v.w*v.w;
    #pragma unroll
    for (int off = 32; off > 0; off >>= 1){
        s  += __shfl_xor(s,  off);
        q2 += __shfl_xor(q2, off);
    }
    float mean = s * (1.f/256.f);
    float var  = q2 * (1.f/256.f) - mean*mean;
    float rs   = rsqrtf(var + 1e-6f);
    f4 gv = reinterpret_cast<const f4*>(g)[lane];
    f4 bv = reinterpret_cast<const f4*>(b)[lane];
    f4 t = (v - mean) * rs;
    t = t * gv + bv;
    uint2 r;
    r.x = pack2(t.x, t.y); r.y = pack2(t.z, t.w);
    *reinterpret_cast<uint2*>(y + row*256 + (size_t)lane*4) = r;
}

// ======== 128x128 GEMM (m97-structure): out = A[M,K] @ Bt[N,K]^T + bias ======
// BK=64; 4 waves in 2x2, each 64x64 (4x4 16x16x32 frags).
// Staging: global_load_lds 16B/lane, LDS linear, source pre-swizzled by
// slot^=(row&7); frag ds_read_b128 applies the same XOR -> conflict-free.
// EPI: 0=store bf16, 1=bf16*scale, 2=gelu->bf16, 3=+resid->fp32
template<int EPI>
__global__ __launch_bounds__(256, 2)
void gemm128_kernel(const u16* __restrict__ A, const u16* __restrict__ Bt,
                    const float* __restrict__ bias, const float* __restrict__ resid,
                    void* __restrict__ outp, int M, int N, int K, float scale)
{
    __shared__ u16 As[128][64];
    __shared__ u16 Bs[128][64];
    const int tid = threadIdx.x;
    const int wv = tid >> 6, lane = tid & 63;
    const int g = lane >> 4, lm = lane & 15;
    const int wr = wv >> 1, wc = wv & 1;
    const int n0 = blockIdx.x * 128, m0 = blockIdx.y * 128;

    const int srow  = lane >> 3;                 // 0..7 within 8-row group
    const int sslot = (lane & 7) ^ srow;         // pre-swizzled source slot

    f32x4 acc[4][4] = {};

    for (int k0 = 0; k0 < K; k0 += 64){
        #pragma unroll
        for (int i = 0; i < 4; i++){
            int rb = wv*32 + i*8;                // 8-row group (wave-uniform)
            gld16(A  + (size_t)(m0 + rb + srow) * K + k0 + sslot*8, &As[rb][0]);
            gld16(Bt + (size_t)(n0 + rb + srow) * K + k0 + sslot*8, &Bs[rb][0]);
        }
        __syncthreads();
        #pragma unroll
        for (int ks = 0; ks < 2; ks++){
            bf16x8 av[4], bv[4];
            #pragma unroll
            for (int mt = 0; mt < 4; mt++){
                int row = wr*64 + mt*16 + lm;
                av[mt] = *reinterpret_cast<const bf16x8*>(&As[row][((ks*4+g) ^ (row&7))*8]);
            }
            #pragma unroll
            for (int nt = 0; nt < 4; nt++){
                int col = wc*64 + nt*16 + lm;
                bv[nt] = *reinterpret_cast<const bf16x8*>(&Bs[col][((ks*4+g) ^ (col&7))*8]);
            }
            #pragma unroll
            for (int mt = 0; mt < 4; mt++)
                #pragma unroll
                for (int nt = 0; nt < 4; nt++)
                    acc[mt][nt] = __builtin_amdgcn_mfma_f32_16x16x32_bf16(av[mt], bv[nt], acc[mt][nt], 0, 0, 0);
        }
        __syncthreads();
    }
    #pragma unroll
    for (int nt = 0; nt < 4; nt++){
        int col = n0 + wc*64 + nt*16 + lm;
        float bc = bias[col];
        #pragma unroll
        for (int mt = 0; mt < 4; mt++){
            #pragma unroll
            for (int r = 0; r < 4; r++){
                int row = m0 + wr*64 + mt*16 + g*4 + r;
                float val = acc[mt][nt][r] + bc;
                if constexpr (EPI == 1) val *= scale;
                if constexpr (EPI == 2) val = 0.5f * val * (1.f + erff(val * 0.70710678118654752f));
                if constexpr (EPI == 3){
                    size_t o = (size_t)row * N + col;
                    reinterpret_cast<float*>(outp)[o] = val + resid[o];
                } else {
                    reinterpret_cast<u16*>(outp)[(size_t)row * N + col] = f2bf(val);
                }
            }
        }
    }
}

// ======== MFMA axial attention. Block = one (b,line); wave = one head. =======
// S^T = mfma(A=K, B=Q): lane holds S[q=tj*16+lm][kk=ti*16+g*4+r]
//   -> softmax over kk = in-lane reduce + shfl_xor(16,32); mask loads are f4.
// P (with 1/sum folded) -> LDS -> standard A-frags for PV = mfma(P, V).
// O returns via LDS (reusing P slab) for coalesced 16B global stores.
// HAXIS also folds the lepe add into the write phase.
// In-place safe (out == v): all v reads staged to LDS before any write.
template<bool HAXIS>
__global__ __launch_bounds__(512, 2)
void attn_mfma_kernel(const u16* __restrict__ q, const u16* __restrict__ k,
                      const u16* __restrict__ v, const float* __restrict__ mask,
                      const u16* __restrict__ lep, u16* __restrict__ out)
{
    __shared__ u16 Kl[8][64][40];   // pad 8: b128 frag reads balanced
    __shared__ u16 Vl[8][64][34];   // pad 2: u16 transpose reads conflict-free
    __shared__ u16 Pl[8][64][72];   // P; later reused as O_lds[8][64][40]
    u16* Ol = &Pl[0][0][0];

    const int tid = threadIdx.x;
    const int lane = tid & 63, wv = tid >> 6;     // wv = head
    const int g = lane >> 4, lm = lane & 15;

    size_t base, RS;
    if constexpr (HAXIS){
        base = (size_t)(blockIdx.x >> 6) * 1048576 + (size_t)(blockIdx.x & 63) * 256;
        RS = 16384;
    } else {
        base = (size_t)blockIdx.x * 16384;
        RS = 256;
    }

    // ---- stage K and V (bf16, coalesced 16B) ----
    #pragma unroll
    for (int rnd = 0; rnd < 4; rnd++){
        int c = rnd*512 + tid;                    // (kk, hd, dhalf)
        int kk = c >> 5, hd = (c >> 2) & 7, dh = c & 3;
        size_t gco = base + (size_t)kk*RS + hd*32 + dh*8;
        uint4 uk = *reinterpret_cast<const uint4*>(k + gco);
        *reinterpret_cast<uint4*>(&Kl[hd][kk][dh*8]) = uk;
        uint4 uv = *reinterpret_cast<const uint4*>(v + gco);
        *reinterpret_cast<uint4*>(&Vl[hd][kk][dh*8]) = uv;
    }
    // ---- Q fragments direct from global (B-operand: col=q, k=d) ----
    bf16x8 qf[4];
    #pragma unroll
    for (int tj = 0; tj < 4; tj++)
        qf[tj] = *reinterpret_cast<const bf16x8*>(q + base + (size_t)(tj*16+lm)*RS + wv*32 + g*8);
    __syncthreads();

    // ---- S^T = K·Q^T : 4(kk-tiles) x 4(q-tiles), K=32 ----
    f32x4 st[4][4];                               // [ti=kk][tj=q]
    #pragma unroll
    for (int ti = 0; ti < 4; ti++){
        bf16x8 kf = *reinterpret_cast<const bf16x8*>(&Kl[wv][ti*16+lm][g*8]);
        #pragma unroll
        for (int tj = 0; tj < 4; tj++){
            f32x4 z = {};
            st[ti][tj] = __builtin_amdgcn_mfma_f32_16x16x32_bf16(kf, qf[tj], z, 0, 0, 0);
        }
    }
    // ---- + mask (f4 loads: kk is the register axis) ----
    #pragma unroll
    for (int tj = 0; tj < 4; tj++){
        const float* mrow = mask + ((size_t)wv*64 + tj*16+lm)*64;
        #pragma unroll
        for (int ti = 0; ti < 4; ti++)
            st[ti][tj] += *reinterpret_cast<const f4*>(mrow + ti*16 + g*4);
    }
    // ---- softmax over kk, fold 1/sum, write P(bf16) to LDS ----
    #pragma unroll
    for (int tj = 0; tj < 4; tj++){
        float mx = -1e30f;
        #pragma unroll
        for (int ti = 0; ti < 4; ti++)
            #pragma unroll
            for (int r = 0; r < 4; r++) mx = fmaxf(mx, st[ti][tj][r]);
        mx = fmaxf(mx, __shfl_xor(mx, 16));
        mx = fmaxf(mx, __shfl_xor(mx, 32));
        float sum = 0.f;
        #pragma unroll
        for (int ti = 0; ti < 4; ti++)
            #pragma unroll
            for (int r = 0; r < 4; r++){
                float p = __expf(st[ti][tj][r] - mx);
                st[ti][tj][r] = p; sum += p;
            }
        sum += __shfl_xor(sum, 16);
        sum += __shfl_xor(sum, 32);
        float inv = 1.f / sum;
        #pragma unroll
        for (int ti = 0; ti < 4; ti++){
            uint2 pw;
            pw.x = pack2(st[ti][tj][0]*inv, st[ti][tj][1]*inv);
            pw.y = pack2(st[ti][tj][2]*inv, st[ti][tj][3]*inv);
            *reinterpret_cast<uint2*>(&Pl[wv][tj*16+lm][ti*16+g*4]) = pw;
        }
    }
    // ---- PV: O[q][d] = sum_kk P[q][kk] V[kk][d] ----
    f32x4 oc[4][2] = {};                          // [q-tile][d-tile]
    #pragma unroll
    for (int kb = 0; kb < 2; kb++){
        bf16x8 vf[2];
        #pragma unroll
        for (int dt = 0; dt < 2; dt++)
            #pragma unroll
            for (int j = 0; j < 8; j++)
                vf[dt][j] = u2b(Vl[wv][kb*32 + g*8 + j][dt*16 + lm]);
        #pragma unroll
        for (int ti2 = 0; ti2 < 4; ti2++){
            bf16x8 pf = *reinterpret_cast<const bf16x8*>(&Pl[wv][ti2*16+lm][kb*32 + g*8]);
            oc[ti2][0] = __builtin_amdgcn_mfma_f32_16x16x32_bf16(pf, vf[0], oc[ti2][0], 0, 0, 0);
            oc[ti2][1] = __builtin_amdgcn_mfma_f32_16x16x32_bf16(pf, vf[1], oc[ti2][1], 0, 0, 0);
        }
    }
    __syncthreads();   // all P reads done before O overwrites the P slab
    #pragma unroll
    for (int ti2 = 0; ti2 < 4; ti2++)
        #pragma unroll
        for (int dt = 0; dt < 2; dt++)
            #pragma unroll
            for (int r = 0; r < 4; r++)
                Ol[((size_t)wv*64 + ti2*16 + g*4 + r)*40 + dt*16 + lm] = f2bf(oc[ti2][dt][r]);
    __syncthreads();
    // ---- coalesced global write (+ lepe on the H-axis pass) ----
    #pragma unroll
    for (int rnd = 0; rnd < 4; rnd++){
        int c = rnd*512 + tid;
        int row = c >> 5, hd = (c >> 2) & 7, dh = c & 3;
        uint4 u = *reinterpret_cast<const uint4*>(&Ol[((size_t)hd*64 + row)*40 + dh*8]);
        size_t gco = base + (size_t)row*RS + hd*32 + dh*8;
        if constexpr (HAXIS){
            uint4 ul = *reinterpret_cast<const uint4*>(lep + gco);
            float a[8], b2[8]; unp8(u, a); unp8(ul, b2);
            u.x = pack2(a[0]+b2[0], a[1]+b2[1]);
            u.y = pack2(a[2]+b2[2], a[3]+b2[3]);
            u.z = pack2(a[4]+b2[4], a[5]+b2[5]);
            u.w = pack2(a[6]+b2[6], a[7]+b2[7]);
        }
        *reinterpret_cast<uint4*>(out + gco) = u;
    }
}

extern "C" void kernel_launch(void* const* d_in, const int* in_sizes, int n_in,
                              void* d_out, int out_size, void* d_ws, size_t ws_size,
                              hipStream_t stream)
{
    const float* x      = (const float*)d_in[0];
    const float* mask_h = (const float*)d_in[1];
    const float* mask_w = (const float*)d_in[2];
    const float* pos_w  = (const float*)d_in[3];
    const float* pos_b  = (const float*)d_in[4];
    const float* ln1_g  = (const float*)d_in[5];
    const float* ln1_b  = (const float*)d_in[6];
    const float* wq     = (const float*)d_in[7];
    const float* bq     = (const float*)d_in[8];
    const float* wk     = (const float*)d_in[9];
    const float* bk     = (const float*)d_in[10];
    const float* wv     = (const float*)d_in[11];
    const float* bv     = (const float*)d_in[12];
    const float* lepe_w = (const float*)d_in[13];
    const float* lepe_b = (const float*)d_in[14];
    const float* wo     = (const float*)d_in[15];
    const float* bo     = (const float*)d_in[16];
    const float* ln2_g  = (const float*)d_in[17];
    const float* ln2_b  = (const float*)d_in[18];
    const float* fc1_w  = (const float*)d_in[19];
    const float* fc1_b  = (const float*)d_in[20];
    const float* fc2_w  = (const float*)d_in[21];
    const float* fc2_b  = (const float*)d_in[22];

    const size_t MB = 1u << 20;
    float* x1 = (float*)d_out;   // fp32 residual lives in d_out (element-wise RMW only)

    int Bc = 1;
    for (int c = 16; c >= 1; c >>= 1){
        if (ws_size >= (2 + 10 * (size_t)c) * MB) { Bc = c; break; }
    }

    char* ws = (char*)d_ws;
    u16* wT  = (u16*)ws;                       // 1.5 MiB bf16 transposed weights
    u16* wqT = wT, *wkT = wT + 65536, *wvT = wT + 131072, *woT = wT + 196608;
    u16* fc1T = wT + 262144, *fc2T = wT + 524288;
    size_t cb = (size_t)Bc * 2 * MB;           // bytes per bf16 chunk buffer
    u16* y   = (u16*)(ws + 2*MB);
    u16* qb  = (u16*)(ws + 2*MB + cb);
    u16* kb  = (u16*)(ws + 2*MB + 2*cb);
    u16* vb  = (u16*)(ws + 2*MB + 3*cb);
    u16* lep = (u16*)(ws + 2*MB + 4*cb);
    u16* hb  = qb;                             // MLP hidden overlays q,k,v,lep

    dim3 blk(256);
    convert_weights_kernel<<<3072, blk, 0, stream>>>(wq, wk, wv, wo, fc1_w, fc2_w, wT);
    posconv_kernel<<<16384, blk, 0, stream>>>(x, pos_w, pos_b, x1);

    const int nchunk = 16 / Bc;
    const int R = Bc * 4096;                   // rows per chunk
    for (int c = 0; c < nchunk; c++){
        float* xc = x1 + (size_t)c * R * 256;
        dim3 gq(2, R/128), gf(8, R/128);       // (N/128, M/128)
        ln_kernel<<<R/4, blk, 0, stream>>>(xc, ln1_g, ln1_b, y);
        gemm128_kernel<0><<<gq, blk, 0, stream>>>(y, wqT, bq, nullptr, qb, R, 256, 256, 1.f);
        gemm128_kernel<1><<<gq, blk, 0, stream>>>(y, wkT, bk, nullptr, kb, R, 256, 256, 0.17677669529663687f);
        gemm128_kernel<0><<<gq, blk, 0, stream>>>(y, wvT, bv, nullptr, vb, R, 256, 256, 1.f);
        lepe_kernel<<<Bc*512, blk, 0, stream>>>(vb, lepe_w, lepe_b, lep);
        attn_mfma_kernel<false><<<Bc*64, 512, 0, stream>>>(qb, kb, vb, mask_w, nullptr, vb); // vo in-place
        attn_mfma_kernel<true ><<<Bc*64, 512, 0, stream>>>(qb, kb, vb, mask_h, lep, vb);     // attn(+lepe) in-place
        // x2 = x1 + attn @ wo + bo
        gemm128_kernel<3><<<gq, blk, 0, stream>>>(vb, woT, bo, xc, (void*)xc, R, 256, 256, 1.f);
        ln_kernel<<<R/4, blk, 0, stream>>>(xc, ln2_g, ln2_b, y);
        gemm128_kernel<2><<<gf, blk, 0, stream>>>(y, fc1T, fc1_b, nullptr, hb, R, 1024, 256, 1.f);
        gemm128_kernel<3><<<gq, blk, 0, stream>>>(hb, fc2T, fc2_b, xc, (void*)xc, R, 256, 1024, 1.f);
    }
}

// Round 10
// 648.529 us; speedup vs baseline: 1.6024x; 1.0269x over previous
//
#include <hip/hip_runtime.h>
#include <hip/hip_bf16.h>
#include <math.h>

typedef unsigned short u16;
typedef unsigned int   u32;
typedef float f4   __attribute__((ext_vector_type(4)));
typedef float f32x4 __attribute__((ext_vector_type(4)));
typedef __bf16 bf16x8 __attribute__((ext_vector_type(8)));

#define BDIM 16
#define HDIM 64
#define WDIM 64
#define CDIM 256
#define NHEAD 8
#define DHEAD 32
#define FDIM 1024
#define MROWS (BDIM*HDIM*WDIM)   // 65536

__device__ inline float blo(u32 u){ return __uint_as_float(u << 16); }
__device__ inline float bhi(u32 u){ return __uint_as_float(u & 0xffff0000u); }

__device__ inline u16 f2bf(float f){
    __bf16 h = (__bf16)f;
    return __builtin_bit_cast(unsigned short, h);
}
__device__ inline __bf16 u2b(u16 x){ return __builtin_bit_cast(__bf16, x); }
__device__ inline u32 pack2(float lo, float hi){
    return (u32)f2bf(lo) | ((u32)f2bf(hi) << 16);
}
__device__ inline void unp8(uint4 u, float* d){
    d[0]=blo(u.x); d[1]=bhi(u.x); d[2]=blo(u.y); d[3]=bhi(u.y);
    d[4]=blo(u.z); d[5]=bhi(u.z); d[6]=blo(u.w); d[7]=bhi(u.w);
}
// async global->LDS, 16B per lane; LDS dest is wave-uniform base + lane*16
__device__ inline void gld16(const void* g, void* l){
    __builtin_amdgcn_global_load_lds(
        (const __attribute__((address_space(1))) void*)g,
        (__attribute__((address_space(3))) void*)l, 16, 0, 0);
}

// ---------------- weight convert + transpose: dst[n*K+k] = bf16(src[k*N+n]) ---
__global__ __launch_bounds__(256)
void convert_weights_kernel(const float* __restrict__ wq, const float* __restrict__ wk,
                            const float* __restrict__ wv, const float* __restrict__ wo,
                            const float* __restrict__ fc1, const float* __restrict__ fc2,
                            u16* __restrict__ wT)
{
    int i = blockIdx.x * 256 + threadIdx.x;      // 0 .. 786431
    const float* src; int K, N, off;
    if (i < 262144) {                 // wq, wk, wv, wo: each 256x256
        int m = i >> 16;
        src = (m==0) ? wq : (m==1) ? wk : (m==2) ? wv : wo;
        K = 256; N = 256; off = i & 65535;
    } else if (i < 524288) {          // fc1: K=256 N=1024
        src = fc1; K = 256; N = 1024; off = i - 262144;
    } else {                          // fc2: K=1024 N=256
        src = fc2; K = 1024; N = 256; off = i - 524288;
    }
    int k = off % K, n = off / K;
    wT[i] = f2bf(src[(size_t)k * N + n]);
}

// ---------------- 3x3 depthwise conv + residual (fp32) -----------------------
__global__ __launch_bounds__(256)
void posconv_kernel(const float* __restrict__ x, const float* __restrict__ w,
                    const float* __restrict__ bias, float* __restrict__ out)
{
    int idx = blockIdx.x * 256 + threadIdx.x;    // B*H*W*(C/4)
    int c = (idx & 63) * 4;
    int p = idx >> 6;
    int wp = p & 63, hp = (p >> 6) & 63, bp = p >> 12;
    f4 acc = *reinterpret_cast<const f4*>(bias + c);
    #pragma unroll
    for (int kh = 0; kh < 3; kh++){
        int hh = hp + kh - 1; if ((unsigned)hh >= 64u) continue;
        #pragma unroll
        for (int kw = 0; kw < 3; kw++){
            int ww = wp + kw - 1; if ((unsigned)ww >= 64u) continue;
            f4 xv = *reinterpret_cast<const f4*>(x + (((size_t)(bp*64 + hh))*64 + ww)*256 + c);
            f4 wv = *reinterpret_cast<const f4*>(w + (size_t)(kh*3 + kw)*256 + c);
            acc += xv * wv;
        }
    }
    f4 ctr = *reinterpret_cast<const f4*>(x + (size_t)p*256 + c);
    *reinterpret_cast<f4*>(out + (size_t)p*256 + c) = ctr + acc;
}

// ---------------- 5x5 depthwise conv on bf16 v -> bf16 lepe ------------------
__global__ __launch_bounds__(256)
void lepe_kernel(const u16* __restrict__ v, const float* __restrict__ w,
                 const float* __restrict__ bias, u16* __restrict__ out)
{
    int idx = blockIdx.x * 256 + threadIdx.x;    // Bc*H*W*(C/8)
    int c = (idx & 31) * 8;
    int p = idx >> 5;
    int wp = p & 63, hp = (p >> 6) & 63, bp = p >> 12;
    float acc[8];
    #pragma unroll
    for (int j = 0; j < 8; j++) acc[j] = bias[c + j];
    #pragma unroll
    for (int kh = 0; kh < 5; kh++){
        int hh = hp + kh - 2; if ((unsigned)hh >= 64u) continue;
        #pragma unroll
        for (int kw = 0; kw < 5; kw++){
            int ww = wp + kw - 2; if ((unsigned)ww >= 64u) continue;
            uint4 u = *reinterpret_cast<const uint4*>(v + (((size_t)(bp*64 + hh))*64 + ww)*256 + c);
            float xv[8]; unp8(u, xv);
            const float* wr = w + (size_t)(kh*5 + kw)*256 + c;
            #pragma unroll
            for (int j = 0; j < 8; j++) acc[j] += xv[j] * wr[j];
        }
    }
    uint4 r;
    r.x = pack2(acc[0],acc[1]); r.y = pack2(acc[2],acc[3]);
    r.z = pack2(acc[4],acc[5]); r.w = pack2(acc[6],acc[7]);
    *reinterpret_cast<uint4*>(out + (size_t)p*256 + c) = r;
}

// ---------------- LayerNorm (fp32 in, bf16 out), 4 rows/block (1 per wave) ---
__global__ __launch_bounds__(256)
void ln_kernel(const float* __restrict__ x, const float* __restrict__ g,
               const float* __restrict__ b, u16* __restrict__ y)
{
    int wid = threadIdx.x >> 6, lane = threadIdx.x & 63;
    size_t row = (size_t)blockIdx.x * 4 + wid;
    f4 v = reinterpret_cast<const f4*>(x + row*256)[lane];
    float s  = v.x + v.y + v.z + v.w;
    float q2 = v.x*v.x + v.y*v.y + v.z*v.z + v.w*v.w;
    #pragma unroll
    for (int off = 32; off > 0; off >>= 1){
        s  += __shfl_xor(s,  off);
        q2 += __shfl_xor(q2, off);
    }
    float mean = s * (1.f/256.f);
    float var  = q2 * (1.f/256.f) - mean*mean;
    float rs   = rsqrtf(var + 1e-6f);
    f4 gv = reinterpret_cast<const f4*>(g)[lane];
    f4 bv = reinterpret_cast<const f4*>(b)[lane];
    f4 t = (v - mean) * rs;
    t = t * gv + bv;
    uint2 r;
    r.x = pack2(t.x, t.y); r.y = pack2(t.z, t.w);
    *reinterpret_cast<uint2*>(y + row*256 + (size_t)lane*4) = r;
}

// ======== 128x128 GEMM (m97-structure): out = A[M,K] @ Bt[N,K]^T + bias ======
// BK=64; 4 waves in 2x2, each 64x64 (4x4 16x16x32 frags).
// Staging: global_load_lds 16B/lane, LDS linear, source pre-swizzled by
// slot^=(row&7); frag ds_read_b128 applies the same XOR -> conflict-free.
// bf16 epilogue (EPI 0/1/2) goes through LDS (stride 132) so global stores are
// 256B-contiguous row segments -> no 32B-segment write amplification / RMW.
// EPI: 0=store bf16, 1=bf16*scale, 2=gelu->bf16, 3=+resid->fp32 (direct, 64B segs)
template<int EPI>
__global__ __launch_bounds__(256, 2)
void gemm128_kernel(const u16* __restrict__ A, const u16* __restrict__ Bt,
                    const float* __restrict__ bias, const float* __restrict__ resid,
                    void* __restrict__ outp, int M, int N, int K, float scale)
{
    __shared__ u16 smem[16896];                  // As[128][64] | Bs[128][64]; reused as C[128][132]
    u16* As = smem;                              // [128][64]
    u16* Bs = smem + 8192;                       // [128][64]
    const int tid = threadIdx.x;
    const int wv = tid >> 6, lane = tid & 63;
    const int g = lane >> 4, lm = lane & 15;
    const int wr = wv >> 1, wc = wv & 1;
    const int n0 = blockIdx.x * 128, m0 = blockIdx.y * 128;

    const int srow  = lane >> 3;                 // 0..7 within 8-row group
    const int sslot = (lane & 7) ^ srow;         // pre-swizzled source slot

    f32x4 acc[4][4] = {};

    for (int k0 = 0; k0 < K; k0 += 64){
        #pragma unroll
        for (int i = 0; i < 4; i++){
            int rb = wv*32 + i*8;                // 8-row group (wave-uniform)
            gld16(A  + (size_t)(m0 + rb + srow) * K + k0 + sslot*8, &As[rb*64]);
            gld16(Bt + (size_t)(n0 + rb + srow) * K + k0 + sslot*8, &Bs[rb*64]);
        }
        __syncthreads();
        #pragma unroll
        for (int ks = 0; ks < 2; ks++){
            bf16x8 av[4], bv[4];
            #pragma unroll
            for (int mt = 0; mt < 4; mt++){
                int row = wr*64 + mt*16 + lm;
                av[mt] = *reinterpret_cast<const bf16x8*>(&As[row*64 + ((ks*4+g) ^ (row&7))*8]);
            }
            #pragma unroll
            for (int nt = 0; nt < 4; nt++){
                int col = wc*64 + nt*16 + lm;
                bv[nt] = *reinterpret_cast<const bf16x8*>(&Bs[col*64 + ((ks*4+g) ^ (col&7))*8]);
            }
            #pragma unroll
            for (int mt = 0; mt < 4; mt++)
                #pragma unroll
                for (int nt = 0; nt < 4; nt++)
                    acc[mt][nt] = __builtin_amdgcn_mfma_f32_16x16x32_bf16(av[mt], bv[nt], acc[mt][nt], 0, 0, 0);
        }
        __syncthreads();
    }

    if constexpr (EPI == 3){
        // fp32 +resid: direct stores are full 64B segments — no LDS pass needed
        #pragma unroll
        for (int nt = 0; nt < 4; nt++){
            int col = n0 + wc*64 + nt*16 + lm;
            float bc = bias[col];
            #pragma unroll
            for (int mt = 0; mt < 4; mt++){
                #pragma unroll
                for (int r = 0; r < 4; r++){
                    int row = m0 + wr*64 + mt*16 + g*4 + r;
                    size_t o = (size_t)row * N + col;
                    reinterpret_cast<float*>(outp)[o] = acc[mt][nt][r] + bc + resid[o];
                }
            }
        }
    } else {
        // bf16: scatter into LDS C-tile (stride 132: <=2-way bank alias = free),
        // then coalesced 16B row-segment stores.
        #pragma unroll
        for (int nt = 0; nt < 4; nt++){
            int col = wc*64 + nt*16 + lm;
            float bc = bias[n0 + col];
            #pragma unroll
            for (int mt = 0; mt < 4; mt++){
                #pragma unroll
                for (int r = 0; r < 4; r++){
                    int row = wr*64 + mt*16 + g*4 + r;
                    float val = acc[mt][nt][r] + bc;
                    if constexpr (EPI == 1) val *= scale;
                    if constexpr (EPI == 2) val = 0.5f * val * (1.f + erff(val * 0.70710678118654752f));
                    smem[row*132 + col] = f2bf(val);
                }
            }
        }
        __syncthreads();
        const int rr = tid >> 4, cs = (tid & 15) * 8;
        #pragma unroll
        for (int pass = 0; pass < 8; pass++){
            int row = pass*16 + rr;
            uint4 u = *reinterpret_cast<const uint4*>(&smem[row*132 + cs]);
            *reinterpret_cast<uint4*>(reinterpret_cast<u16*>(outp) + (size_t)(m0+row)*N + n0 + cs) = u;
        }
    }
}

// ======== MFMA axial attention. Block = one (b,line); wave = one head. =======
// S^T = mfma(A=K, B=Q): lane holds S[q=tj*16+lm][kk=ti*16+g*4+r]
//   -> softmax over kk = in-lane reduce + shfl_xor(16,32); mask loads are f4.
// P (with 1/sum folded) -> LDS -> standard A-frags for PV = mfma(P, V).
// O returns via LDS (reusing P slab) for coalesced 16B global stores.
// HAXIS also folds the lepe add into the write phase.
// In-place safe (out == v): all v reads staged to LDS before any write.
template<bool HAXIS>
__global__ __launch_bounds__(512, 2)
void attn_mfma_kernel(const u16* __restrict__ q, const u16* __restrict__ k,
                      const u16* __restrict__ v, const float* __restrict__ mask,
                      const u16* __restrict__ lep, u16* __restrict__ out)
{
    __shared__ u16 Kl[8][64][40];   // pad 8: b128 frag reads balanced
    __shared__ u16 Vl[8][64][34];   // pad 2: u16 transpose reads conflict-free
    __shared__ u16 Pl[8][64][72];   // P; later reused as O_lds[8][64][40]
    u16* Ol = &Pl[0][0][0];

    const int tid = threadIdx.x;
    const int lane = tid & 63, wv = tid >> 6;     // wv = head
    const int g = lane >> 4, lm = lane & 15;

    size_t base, RS;
    if constexpr (HAXIS){
        base = (size_t)(blockIdx.x >> 6) * 1048576 + (size_t)(blockIdx.x & 63) * 256;
        RS = 16384;
    } else {
        base = (size_t)blockIdx.x * 16384;
        RS = 256;
    }

    // ---- stage K and V (bf16, coalesced 16B) ----
    #pragma unroll
    for (int rnd = 0; rnd < 4; rnd++){
        int c = rnd*512 + tid;                    // (kk, hd, dhalf)
        int kk = c >> 5, hd = (c >> 2) & 7, dh = c & 3;
        size_t gco = base + (size_t)kk*RS + hd*32 + dh*8;
        uint4 uk = *reinterpret_cast<const uint4*>(k + gco);
        *reinterpret_cast<uint4*>(&Kl[hd][kk][dh*8]) = uk;
        uint4 uv = *reinterpret_cast<const uint4*>(v + gco);
        *reinterpret_cast<uint4*>(&Vl[hd][kk][dh*8]) = uv;
    }
    // ---- Q fragments direct from global (B-operand: col=q, k=d) ----
    bf16x8 qf[4];
    #pragma unroll
    for (int tj = 0; tj < 4; tj++)
        qf[tj] = *reinterpret_cast<const bf16x8*>(q + base + (size_t)(tj*16+lm)*RS + wv*32 + g*8);
    __syncthreads();

    // ---- S^T = K·Q^T : 4(kk-tiles) x 4(q-tiles), K=32 ----
    f32x4 st[4][4];                               // [ti=kk][tj=q]
    #pragma unroll
    for (int ti = 0; ti < 4; ti++){
        bf16x8 kf = *reinterpret_cast<const bf16x8*>(&Kl[wv][ti*16+lm][g*8]);
        #pragma unroll
        for (int tj = 0; tj < 4; tj++){
            f32x4 z = {};
            st[ti][tj] = __builtin_amdgcn_mfma_f32_16x16x32_bf16(kf, qf[tj], z, 0, 0, 0);
        }
    }
    // ---- + mask (f4 loads: kk is the register axis) ----
    #pragma unroll
    for (int tj = 0; tj < 4; tj++){
        const float* mrow = mask + ((size_t)wv*64 + tj*16+lm)*64;
        #pragma unroll
        for (int ti = 0; ti < 4; ti++)
            st[ti][tj] += *reinterpret_cast<const f4*>(mrow + ti*16 + g*4);
    }
    // ---- softmax over kk, fold 1/sum, write P(bf16) to LDS ----
    #pragma unroll
    for (int tj = 0; tj < 4; tj++){
        float mx = -1e30f;
        #pragma unroll
        for (int ti = 0; ti < 4; ti++)
            #pragma unroll
            for (int r = 0; r < 4; r++) mx = fmaxf(mx, st[ti][tj][r]);
        mx = fmaxf(mx, __shfl_xor(mx, 16));
        mx = fmaxf(mx, __shfl_xor(mx, 32));
        float sum = 0.f;
        #pragma unroll
        for (int ti = 0; ti < 4; ti++)
            #pragma unroll
            for (int r = 0; r < 4; r++){
                float p = __expf(st[ti][tj][r] - mx);
                st[ti][tj][r] = p; sum += p;
            }
        sum += __shfl_xor(sum, 16);
        sum += __shfl_xor(sum, 32);
        float inv = 1.f / sum;
        #pragma unroll
        for (int ti = 0; ti < 4; ti++){
            uint2 pw;
            pw.x = pack2(st[ti][tj][0]*inv, st[ti][tj][1]*inv);
            pw.y = pack2(st[ti][tj][2]*inv, st[ti][tj][3]*inv);
            *reinterpret_cast<uint2*>(&Pl[wv][tj*16+lm][ti*16+g*4]) = pw;
        }
    }
    // ---- PV: O[q][d] = sum_kk P[q][kk] V[kk][d] ----
    f32x4 oc[4][2] = {};                          // [q-tile][d-tile]
    #pragma unroll
    for (int kb = 0; kb < 2; kb++){
        bf16x8 vf[2];
        #pragma unroll
        for (int dt = 0; dt < 2; dt++)
            #pragma unroll
            for (int j = 0; j < 8; j++)
                vf[dt][j] = u2b(Vl[wv][kb*32 + g*8 + j][dt*16 + lm]);
        #pragma unroll
        for (int ti2 = 0; ti2 < 4; ti2++){
            bf16x8 pf = *reinterpret_cast<const bf16x8*>(&Pl[wv][ti2*16+lm][kb*32 + g*8]);
            oc[ti2][0] = __builtin_amdgcn_mfma_f32_16x16x32_bf16(pf, vf[0], oc[ti2][0], 0, 0, 0);
            oc[ti2][1] = __builtin_amdgcn_mfma_f32_16x16x32_bf16(pf, vf[1], oc[ti2][1], 0, 0, 0);
        }
    }
    __syncthreads();   // all P reads done before O overwrites the P slab
    #pragma unroll
    for (int ti2 = 0; ti2 < 4; ti2++)
        #pragma unroll
        for (int dt = 0; dt < 2; dt++)
            #pragma unroll
            for (int r = 0; r < 4; r++)
                Ol[((size_t)wv*64 + ti2*16 + g*4 + r)*40 + dt*16 + lm] = f2bf(oc[ti2][dt][r]);
    __syncthreads();
    // ---- coalesced global write (+ lepe on the H-axis pass) ----
    #pragma unroll
    for (int rnd = 0; rnd < 4; rnd++){
        int c = rnd*512 + tid;
        int row = c >> 5, hd = (c >> 2) & 7, dh = c & 3;
        uint4 u = *reinterpret_cast<const uint4*>(&Ol[((size_t)hd*64 + row)*40 + dh*8]);
        size_t gco = base + (size_t)row*RS + hd*32 + dh*8;
        if constexpr (HAXIS){
            uint4 ul = *reinterpret_cast<const uint4*>(lep + gco);
            float a[8], b2[8]; unp8(u, a); unp8(ul, b2);
            u.x = pack2(a[0]+b2[0], a[1]+b2[1]);
            u.y = pack2(a[2]+b2[2], a[3]+b2[3]);
            u.z = pack2(a[4]+b2[4], a[5]+b2[5]);
            u.w = pack2(a[6]+b2[6], a[7]+b2[7]);
        }
        *reinterpret_cast<uint4*>(out + gco) = u;
    }
}

extern "C" void kernel_launch(void* const* d_in, const int* in_sizes, int n_in,
                              void* d_out, int out_size, void* d_ws, size_t ws_size,
                              hipStream_t stream)
{
    const float* x      = (const float*)d_in[0];
    const float* mask_h = (const float*)d_in[1];
    const float* mask_w = (const float*)d_in[2];
    const float* pos_w  = (const float*)d_in[3];
    const float* pos_b  = (const float*)d_in[4];
    const float* ln1_g  = (const float*)d_in[5];
    const float* ln1_b  = (const float*)d_in[6];
    const float* wq     = (const float*)d_in[7];
    const float* bq     = (const float*)d_in[8];
    const float* wk     = (const float*)d_in[9];
    const float* bk     = (const float*)d_in[10];
    const float* wv     = (const float*)d_in[11];
    const float* bv     = (const float*)d_in[12];
    const float* lepe_w = (const float*)d_in[13];
    const float* lepe_b = (const float*)d_in[14];
    const float* wo     = (const float*)d_in[15];
    const float* bo     = (const float*)d_in[16];
    const float* ln2_g  = (const float*)d_in[17];
    const float* ln2_b  = (const float*)d_in[18];
    const float* fc1_w  = (const float*)d_in[19];
    const float* fc1_b  = (const float*)d_in[20];
    const float* fc2_w  = (const float*)d_in[21];
    const float* fc2_b  = (const float*)d_in[22];

    const size_t MB = 1u << 20;
    float* x1 = (float*)d_out;   // fp32 residual lives in d_out (element-wise RMW only)

    int Bc = 1;
    for (int c = 16; c >= 1; c >>= 1){
        if (ws_size >= (2 + 10 * (size_t)c) * MB) { Bc = c; break; }
    }

    char* ws = (char*)d_ws;
    u16* wT  = (u16*)ws;                       // 1.5 MiB bf16 transposed weights
    u16* wqT = wT, *wkT = wT + 65536, *wvT = wT + 131072, *woT = wT + 196608;
    u16* fc1T = wT + 262144, *fc2T = wT + 524288;
    size_t cb = (size_t)Bc * 2 * MB;           // bytes per bf16 chunk buffer
    u16* y   = (u16*)(ws + 2*MB);
    u16* qb  = (u16*)(ws + 2*MB + cb);
    u16* kb  = (u16*)(ws + 2*MB + 2*cb);
    u16* vb  = (u16*)(ws + 2*MB + 3*cb);
    u16* lep = (u16*)(ws + 2*MB + 4*cb);
    u16* hb  = qb;                             // MLP hidden overlays q,k,v,lep

    dim3 blk(256);
    convert_weights_kernel<<<3072, blk, 0, stream>>>(wq, wk, wv, wo, fc1_w, fc2_w, wT);
    posconv_kernel<<<16384, blk, 0, stream>>>(x, pos_w, pos_b, x1);

    const int nchunk = 16 / Bc;
    const int R = Bc * 4096;                   // rows per chunk
    for (int c = 0; c < nchunk; c++){
        float* xc = x1 + (size_t)c * R * 256;
        dim3 gq(2, R/128), gf(8, R/128);       // (N/128, M/128)
        ln_kernel<<<R/4, blk, 0, stream>>>(xc, ln1_g, ln1_b, y);
        gemm128_kernel<0><<<gq, blk, 0, stream>>>(y, wqT, bq, nullptr, qb, R, 256, 256, 1.f);
        gemm128_kernel<1><<<gq, blk, 0, stream>>>(y, wkT, bk, nullptr, kb, R, 256, 256, 0.17677669529663687f);
        gemm128_kernel<0><<<gq, blk, 0, stream>>>(y, wvT, bv, nullptr, vb, R, 256, 256, 1.f);
        lepe_kernel<<<Bc*512, blk, 0, stream>>>(vb, lepe_w, lepe_b, lep);
        attn_mfma_kernel<false><<<Bc*64, 512, 0, stream>>>(qb, kb, vb, mask_w, nullptr, vb); // vo in-place
        attn_mfma_kernel<true ><<<Bc*64, 512, 0, stream>>>(qb, kb, vb, mask_h, lep, vb);     // attn(+lepe) in-place
        // x2 = x1 + attn @ wo + bo
        gemm128_kernel<3><<<gq, blk, 0, stream>>>(vb, woT, bo, xc, (void*)xc, R, 256, 256, 1.f);
        ln_kernel<<<R/4, blk, 0, stream>>>(xc, ln2_g, ln2_b, y);
        gemm128_kernel<2><<<gf, blk, 0, stream>>>(y, fc1T, fc1_b, nullptr, hb, R, 1024, 256, 1.f);
        gemm128_kernel<3><<<gq, blk, 0, stream>>>(hb, fc2T, fc2_b, xc, (void*)xc, R, 256, 1024, 1.f);
    }
}

// Round 11
// 590.537 us; speedup vs baseline: 1.7598x; 1.0982x over previous
//
#include <hip/hip_runtime.h>
#include <hip/hip_bf16.h>
#include <math.h>

typedef unsigned short u16;
typedef unsigned int   u32;
typedef float f4   __attribute__((ext_vector_type(4)));
typedef float f32x4 __attribute__((ext_vector_type(4)));
typedef __bf16 bf16x8 __attribute__((ext_vector_type(8)));

#define BDIM 16
#define HDIM 64
#define WDIM 64
#define CDIM 256
#define NHEAD 8
#define DHEAD 32
#define FDIM 1024
#define MROWS (BDIM*HDIM*WDIM)   // 65536

__device__ inline float blo(u32 u){ return __uint_as_float(u << 16); }
__device__ inline float bhi(u32 u){ return __uint_as_float(u & 0xffff0000u); }

__device__ inline u16 f2bf(float f){
    __bf16 h = (__bf16)f;
    return __builtin_bit_cast(unsigned short, h);
}
__device__ inline __bf16 u2b(u16 x){ return __builtin_bit_cast(__bf16, x); }
__device__ inline u32 pack2(float lo, float hi){
    return (u32)f2bf(lo) | ((u32)f2bf(hi) << 16);
}
__device__ inline void unp8(uint4 u, float* d){
    d[0]=blo(u.x); d[1]=bhi(u.x); d[2]=blo(u.y); d[3]=bhi(u.y);
    d[4]=blo(u.z); d[5]=bhi(u.z); d[6]=blo(u.w); d[7]=bhi(u.w);
}
// async global->LDS, 16B per lane; LDS dest is wave-uniform base + lane*16
__device__ inline void gld16(const void* g, void* l){
    __builtin_amdgcn_global_load_lds(
        (const __attribute__((address_space(1))) void*)g,
        (__attribute__((address_space(3))) void*)l, 16, 0, 0);
}

// -------- weight convert+transpose (k-scale folded into wkT) + fused qkv bias
__global__ __launch_bounds__(256)
void convert_weights_kernel(const float* __restrict__ wq, const float* __restrict__ wk,
                            const float* __restrict__ wv, const float* __restrict__ wo,
                            const float* __restrict__ fc1, const float* __restrict__ fc2,
                            const float* __restrict__ bq, const float* __restrict__ bk,
                            const float* __restrict__ bv,
                            u16* __restrict__ wT, float* __restrict__ bqkv)
{
    int i = blockIdx.x * 256 + threadIdx.x;
    const float SCL = 0.17677669529663687f;     // d^-0.5
    if (i < 786432){
        const float* src; int K, N, off; float s = 1.f;
        if (i < 262144){                        // wq,wk,wv,wo: 256x256 each
            int m = i >> 16;
            src = (m==0) ? wq : (m==1) ? wk : (m==2) ? wv : wo;
            if (m == 1) s = SCL;
            K = 256; N = 256; off = i & 65535;
        } else if (i < 524288){ src = fc1; K = 256; N = 1024; off = i - 262144; }
        else                  { src = fc2; K = 1024; N = 256; off = i - 524288; }
        int k = off % K, n = off / K;
        wT[i] = f2bf(src[(size_t)k * N + n] * s);
    } else {
        int j = i - 786432;
        if (j < 768)
            bqkv[j] = (j < 256) ? bq[j] : (j < 512) ? bk[j-256]*SCL : bv[j-512];
    }
}

// -------- fused 3x3 depthwise conv + residual + LayerNorm1 -------------------
// One wave = one pixel (64 lanes x 4 ch). Writes x1 (fp32 resid) and y (bf16 LN).
__global__ __launch_bounds__(256)
void posconv_ln1_kernel(const float* __restrict__ x, const float* __restrict__ w,
                        const float* __restrict__ bias,
                        const float* __restrict__ lg, const float* __restrict__ lb,
                        float* __restrict__ x1, u16* __restrict__ y)
{
    int idx = blockIdx.x * 256 + threadIdx.x;
    int lane = threadIdx.x & 63;
    int c = lane * 4;
    int p = idx >> 6;
    int wp = p & 63, hp = (p >> 6) & 63, bp = p >> 12;
    f4 acc = *reinterpret_cast<const f4*>(bias + c);
    #pragma unroll
    for (int kh = 0; kh < 3; kh++){
        int hh = hp + kh - 1; if ((unsigned)hh >= 64u) continue;
        #pragma unroll
        for (int kw = 0; kw < 3; kw++){
            int ww = wp + kw - 1; if ((unsigned)ww >= 64u) continue;
            f4 xv = *reinterpret_cast<const f4*>(x + (((size_t)(bp*64 + hh))*64 + ww)*256 + c);
            f4 wv = *reinterpret_cast<const f4*>(w + (size_t)(kh*3 + kw)*256 + c);
            acc += xv * wv;
        }
    }
    f4 ctr = *reinterpret_cast<const f4*>(x + (size_t)p*256 + c);
    f4 v = ctr + acc;
    *reinterpret_cast<f4*>(x1 + (size_t)p*256 + c) = v;
    float s  = v.x + v.y + v.z + v.w;
    float q2 = v.x*v.x + v.y*v.y + v.z*v.z + v.w*v.w;
    #pragma unroll
    for (int off = 32; off > 0; off >>= 1){
        s  += __shfl_xor(s,  off);
        q2 += __shfl_xor(q2, off);
    }
    float mean = s * (1.f/256.f);
    float var  = q2 * (1.f/256.f) - mean*mean;
    float rs   = rsqrtf(var + 1e-6f);
    f4 gv = reinterpret_cast<const f4*>(lg)[lane];
    f4 bv = reinterpret_cast<const f4*>(lb)[lane];
    f4 t = (v - mean) * rs * gv + bv;
    uint2 r;
    r.x = pack2(t.x, t.y); r.y = pack2(t.z, t.w);
    *reinterpret_cast<uint2*>(y + (size_t)p*256 + (size_t)lane*4) = r;
}

// -------- 5x5 depthwise conv on v (strided inside qkv[.,768]) -> lepe --------
__global__ __launch_bounds__(256)
void lepe_kernel(const u16* __restrict__ qkv, const float* __restrict__ w,
                 const float* __restrict__ bias, u16* __restrict__ out)
{
    int idx = blockIdx.x * 256 + threadIdx.x;    // R*H*W*(C/8)
    int c = (idx & 31) * 8;
    int p = idx >> 5;
    int wp = p & 63, hp = (p >> 6) & 63, bp = p >> 12;
    float acc[8];
    #pragma unroll
    for (int j = 0; j < 8; j++) acc[j] = bias[c + j];
    #pragma unroll
    for (int kh = 0; kh < 5; kh++){
        int hh = hp + kh - 2; if ((unsigned)hh >= 64u) continue;
        #pragma unroll
        for (int kw = 0; kw < 5; kw++){
            int ww = wp + kw - 2; if ((unsigned)ww >= 64u) continue;
            uint4 u = *reinterpret_cast<const uint4*>(
                qkv + (((size_t)(bp*64 + hh))*64 + ww)*768 + 512 + c);
            float xv[8]; unp8(u, xv);
            const float* wr = w + (size_t)(kh*5 + kw)*256 + c;
            #pragma unroll
            for (int j = 0; j < 8; j++) acc[j] += xv[j] * wr[j];
        }
    }
    uint4 r;
    r.x = pack2(acc[0],acc[1]); r.y = pack2(acc[2],acc[3]);
    r.z = pack2(acc[4],acc[5]); r.w = pack2(acc[6],acc[7]);
    *reinterpret_cast<uint4*>(out + (size_t)p*256 + c) = r;
}

// -------- LayerNorm (fp32 in, bf16 out), 1 row per wave ----------------------
__global__ __launch_bounds__(256)
void ln_kernel(const float* __restrict__ x, const float* __restrict__ g,
               const float* __restrict__ b, u16* __restrict__ y)
{
    int wid = threadIdx.x >> 6, lane = threadIdx.x & 63;
    size_t row = (size_t)blockIdx.x * 4 + wid;
    f4 v = reinterpret_cast<const f4*>(x + row*256)[lane];
    float s  = v.x + v.y + v.z + v.w;
    float q2 = v.x*v.x + v.y*v.y + v.z*v.z + v.w*v.w;
    #pragma unroll
    for (int off = 32; off > 0; off >>= 1){
        s  += __shfl_xor(s,  off);
        q2 += __shfl_xor(q2, off);
    }
    float mean = s * (1.f/256.f);
    float var  = q2 * (1.f/256.f) - mean*mean;
    float rs   = rsqrtf(var + 1e-6f);
    f4 gv = reinterpret_cast<const f4*>(g)[lane];
    f4 bv = reinterpret_cast<const f4*>(b)[lane];
    f4 t = (v - mean) * rs;
    t = t * gv + bv;
    uint2 r;
    r.x = pack2(t.x, t.y); r.y = pack2(t.z, t.w);
    *reinterpret_cast<uint2*>(y + row*256 + (size_t)lane*4) = r;
}

// ======== 128x128 GEMM: out = A[M,K](lda) @ Bt[N,K]^T + bias =================
// XCD-aware bijective block swizzle (all grids have nwg%8==0).
// Staging: global_load_lds 16B, linear LDS, source pre-swizzled slot^=(row&7);
// frag ds_read_b128 applies the same XOR. bf16 epilogue via LDS C-tile (stride
// 132) for 256B-contiguous stores. EPI: 0=bf16, 2=gelu->bf16, 3=+resid->fp32.
template<int EPI>
__global__ __launch_bounds__(256, 2)
void gemm128_kernel(const u16* __restrict__ A, int lda, const u16* __restrict__ Bt,
                    const float* __restrict__ bias, const float* __restrict__ resid,
                    void* __restrict__ outp, int M, int N, int K)
{
    __shared__ u16 smem[16896];                  // As[128][64] | Bs[128][64]; C[128][132]
    u16* As = smem;
    u16* Bs = smem + 8192;
    const int tid = threadIdx.x;
    const int wv = tid >> 6, lane = tid & 63;
    const int g = lane >> 4, lm = lane & 15;
    const int wr = wv >> 1, wc = wv & 1;

    // XCD swizzle: orig linear id w dispatched to XCD w%8; remap so each XCD
    // walks consecutive N-tiles of one M-panel (A-panel L2 reuse).
    int nbx = gridDim.x;
    int wg = blockIdx.y * nbx + blockIdx.x;
    int cpx = (nbx * gridDim.y) >> 3;
    wg = (wg & 7) * cpx + (wg >> 3);
    const int n0 = (wg % nbx) * 128, m0 = (wg / nbx) * 128;

    const int srow  = lane >> 3;
    const int sslot = (lane & 7) ^ srow;

    f32x4 acc[4][4] = {};

    for (int k0 = 0; k0 < K; k0 += 64){
        #pragma unroll
        for (int i = 0; i < 4; i++){
            int rb = wv*32 + i*8;
            gld16(A  + (size_t)(m0 + rb + srow) * lda + k0 + sslot*8, &As[rb*64]);
            gld16(Bt + (size_t)(n0 + rb + srow) * K   + k0 + sslot*8, &Bs[rb*64]);
        }
        __syncthreads();
        #pragma unroll
        for (int ks = 0; ks < 2; ks++){
            bf16x8 av[4], bv[4];
            #pragma unroll
            for (int mt = 0; mt < 4; mt++){
                int row = wr*64 + mt*16 + lm;
                av[mt] = *reinterpret_cast<const bf16x8*>(&As[row*64 + ((ks*4+g) ^ (row&7))*8]);
            }
            #pragma unroll
            for (int nt = 0; nt < 4; nt++){
                int col = wc*64 + nt*16 + lm;
                bv[nt] = *reinterpret_cast<const bf16x8*>(&Bs[col*64 + ((ks*4+g) ^ (col&7))*8]);
            }
            #pragma unroll
            for (int mt = 0; mt < 4; mt++)
                #pragma unroll
                for (int nt = 0; nt < 4; nt++)
                    acc[mt][nt] = __builtin_amdgcn_mfma_f32_16x16x32_bf16(av[mt], bv[nt], acc[mt][nt], 0, 0, 0);
        }
        __syncthreads();
    }

    if constexpr (EPI == 3){
        #pragma unroll
        for (int nt = 0; nt < 4; nt++){
            int col = n0 + wc*64 + nt*16 + lm;
            float bc = bias[col];
            #pragma unroll
            for (int mt = 0; mt < 4; mt++){
                #pragma unroll
                for (int r = 0; r < 4; r++){
                    int row = m0 + wr*64 + mt*16 + g*4 + r;
                    size_t o = (size_t)row * N + col;
                    reinterpret_cast<float*>(outp)[o] = acc[mt][nt][r] + bc + resid[o];
                }
            }
        }
    } else {
        #pragma unroll
        for (int nt = 0; nt < 4; nt++){
            int col = wc*64 + nt*16 + lm;
            float bc = bias[n0 + col];
            #pragma unroll
            for (int mt = 0; mt < 4; mt++){
                #pragma unroll
                for (int r = 0; r < 4; r++){
                    int row = wr*64 + mt*16 + g*4 + r;
                    float val = acc[mt][nt][r] + bc;
                    if constexpr (EPI == 2) val = 0.5f * val * (1.f + erff(val * 0.70710678118654752f));
                    smem[row*132 + col] = f2bf(val);
                }
            }
        }
        __syncthreads();
        const int rr = tid >> 4, cs = (tid & 15) * 8;
        #pragma unroll
        for (int pass = 0; pass < 8; pass++){
            int row = pass*16 + rr;
            uint4 u = *reinterpret_cast<const uint4*>(&smem[row*132 + cs]);
            *reinterpret_cast<uint4*>(reinterpret_cast<u16*>(outp) + (size_t)(m0+row)*N + n0 + cs) = u;
        }
    }
}

// ======== MFMA axial attention on interleaved qkv[M][768] ====================
// q/k/v at col 0/256/512; W-axis row stride 768, H-axis 64*768.
// S^T = mfma(K,Q); in-register softmax; P->LDS->PV; O via LDS for coalesced
// stores. HAXIS folds lepe (compact [M][256]) into the write. In-place on v.
template<bool HAXIS>
__global__ __launch_bounds__(512, 2)
void attn_mfma_kernel(u16* __restrict__ qkv, const float* __restrict__ mask,
                      const u16* __restrict__ lep)
{
    __shared__ u16 Kl[8][64][40];
    __shared__ u16 Vl[8][64][34];
    __shared__ u16 Pl[8][64][72];
    u16* Ol = &Pl[0][0][0];

    const int tid = threadIdx.x;
    const int lane = tid & 63, wv = tid >> 6;
    const int g = lane >> 4, lm = lane & 15;

    size_t base, RS, lbase = 0, LRS = 0;
    if constexpr (HAXIS){
        int b = blockIdx.x >> 6, wcc = blockIdx.x & 63;
        base  = (size_t)b * 3145728 + (size_t)wcc * 768;   // b*64*64*768 + w*768
        RS    = 49152;                                     // 64*768
        lbase = (size_t)b * 1048576 + (size_t)wcc * 256;
        LRS   = 16384;
    } else {
        base = (size_t)blockIdx.x * 49152;                 // line * 64*768
        RS   = 768;
    }
    const u16* q = qkv + base;
    const u16* k = qkv + base + 256;
    u16* v = qkv + base + 512;

    // ---- stage K and V ----
    #pragma unroll
    for (int rnd = 0; rnd < 4; rnd++){
        int c = rnd*512 + tid;                    // (kk, hd, dhalf)
        int kk = c >> 5, hd = (c >> 2) & 7, dh = c & 3;
        size_t gco = (size_t)kk*RS + hd*32 + dh*8;
        uint4 uk = *reinterpret_cast<const uint4*>(k + gco);
        *reinterpret_cast<uint4*>(&Kl[hd][kk][dh*8]) = uk;
        uint4 uv = *reinterpret_cast<const uint4*>(v + gco);
        *reinterpret_cast<uint4*>(&Vl[hd][kk][dh*8]) = uv;
    }
    // ---- Q fragments direct from global ----
    bf16x8 qf[4];
    #pragma unroll
    for (int tj = 0; tj < 4; tj++)
        qf[tj] = *reinterpret_cast<const bf16x8*>(q + (size_t)(tj*16+lm)*RS + wv*32 + g*8);
    __syncthreads();

    // ---- S^T = K·Q^T ----
    f32x4 st[4][4];
    #pragma unroll
    for (int ti = 0; ti < 4; ti++){
        bf16x8 kf = *reinterpret_cast<const bf16x8*>(&Kl[wv][ti*16+lm][g*8]);
        #pragma unroll
        for (int tj = 0; tj < 4; tj++){
            f32x4 z = {};
            st[ti][tj] = __builtin_amdgcn_mfma_f32_16x16x32_bf16(kf, qf[tj], z, 0, 0, 0);
        }
    }
    // ---- + mask ----
    #pragma unroll
    for (int tj = 0; tj < 4; tj++){
        const float* mrow = mask + ((size_t)wv*64 + tj*16+lm)*64;
        #pragma unroll
        for (int ti = 0; ti < 4; ti++)
            st[ti][tj] += *reinterpret_cast<const f4*>(mrow + ti*16 + g*4);
    }
    // ---- softmax over kk; P(bf16, 1/sum folded) -> LDS ----
    #pragma unroll
    for (int tj = 0; tj < 4; tj++){
        float mx = -1e30f;
        #pragma unroll
        for (int ti = 0; ti < 4; ti++)
            #pragma unroll
            for (int r = 0; r < 4; r++) mx = fmaxf(mx, st[ti][tj][r]);
        mx = fmaxf(mx, __shfl_xor(mx, 16));
        mx = fmaxf(mx, __shfl_xor(mx, 32));
        float sum = 0.f;
        #pragma unroll
        for (int ti = 0; ti < 4; ti++)
            #pragma unroll
            for (int r = 0; r < 4; r++){
                float p = __expf(st[ti][tj][r] - mx);
                st[ti][tj][r] = p; sum += p;
            }
        sum += __shfl_xor(sum, 16);
        sum += __shfl_xor(sum, 32);
        float inv = 1.f / sum;
        #pragma unroll
        for (int ti = 0; ti < 4; ti++){
            uint2 pw;
            pw.x = pack2(st[ti][tj][0]*inv, st[ti][tj][1]*inv);
            pw.y = pack2(st[ti][tj][2]*inv, st[ti][tj][3]*inv);
            *reinterpret_cast<uint2*>(&Pl[wv][tj*16+lm][ti*16+g*4]) = pw;
        }
    }
    // ---- PV ----
    f32x4 oc[4][2] = {};
    #pragma unroll
    for (int kb = 0; kb < 2; kb++){
        bf16x8 vf[2];
        #pragma unroll
        for (int dt = 0; dt < 2; dt++)
            #pragma unroll
            for (int j = 0; j < 8; j++)
                vf[dt][j] = u2b(Vl[wv][kb*32 + g*8 + j][dt*16 + lm]);
        #pragma unroll
        for (int ti2 = 0; ti2 < 4; ti2++){
            bf16x8 pf = *reinterpret_cast<const bf16x8*>(&Pl[wv][ti2*16+lm][kb*32 + g*8]);
            oc[ti2][0] = __builtin_amdgcn_mfma_f32_16x16x32_bf16(pf, vf[0], oc[ti2][0], 0, 0, 0);
            oc[ti2][1] = __builtin_amdgcn_mfma_f32_16x16x32_bf16(pf, vf[1], oc[ti2][1], 0, 0, 0);
        }
    }
    __syncthreads();
    #pragma unroll
    for (int ti2 = 0; ti2 < 4; ti2++)
        #pragma unroll
        for (int dt = 0; dt < 2; dt++)
            #pragma unroll
            for (int r = 0; r < 4; r++)
                Ol[((size_t)wv*64 + ti2*16 + g*4 + r)*40 + dt*16 + lm] = f2bf(oc[ti2][dt][r]);
    __syncthreads();
    // ---- coalesced write (+ lepe on H pass) ----
    #pragma unroll
    for (int rnd = 0; rnd < 4; rnd++){
        int c = rnd*512 + tid;
        int row = c >> 5, hd = (c >> 2) & 7, dh = c & 3;
        uint4 u = *reinterpret_cast<const uint4*>(&Ol[((size_t)hd*64 + row)*40 + dh*8]);
        if constexpr (HAXIS){
            uint4 ul = *reinterpret_cast<const uint4*>(lep + lbase + (size_t)row*LRS + hd*32 + dh*8);
            float a[8], b2[8]; unp8(u, a); unp8(ul, b2);
            u.x = pack2(a[0]+b2[0], a[1]+b2[1]);
            u.y = pack2(a[2]+b2[2], a[3]+b2[3]);
            u.z = pack2(a[4]+b2[4], a[5]+b2[5]);
            u.w = pack2(a[6]+b2[6], a[7]+b2[7]);
        }
        *reinterpret_cast<uint4*>(v + (size_t)row*RS + hd*32 + dh*8) = u;
    }
}

extern "C" void kernel_launch(void* const* d_in, const int* in_sizes, int n_in,
                              void* d_out, int out_size, void* d_ws, size_t ws_size,
                              hipStream_t stream)
{
    const float* x      = (const float*)d_in[0];
    const float* mask_h = (const float*)d_in[1];
    const float* mask_w = (const float*)d_in[2];
    const float* pos_w  = (const float*)d_in[3];
    const float* pos_b  = (const float*)d_in[4];
    const float* ln1_g  = (const float*)d_in[5];
    const float* ln1_b  = (const float*)d_in[6];
    const float* wq     = (const float*)d_in[7];
    const float* bq     = (const float*)d_in[8];
    const float* wk     = (const float*)d_in[9];
    const float* bk     = (const float*)d_in[10];
    const float* wv     = (const float*)d_in[11];
    const float* bv     = (const float*)d_in[12];
    const float* lepe_w = (const float*)d_in[13];
    const float* lepe_b = (const float*)d_in[14];
    const float* wo     = (const float*)d_in[15];
    const float* bo     = (const float*)d_in[16];
    const float* ln2_g  = (const float*)d_in[17];
    const float* ln2_b  = (const float*)d_in[18];
    const float* fc1_w  = (const float*)d_in[19];
    const float* fc1_b  = (const float*)d_in[20];
    const float* fc2_w  = (const float*)d_in[21];
    const float* fc2_b  = (const float*)d_in[22];

    const size_t MB = 1u << 20;
    float* x1 = (float*)d_out;   // fp32 residual lives in d_out (element-wise RMW only)

    int Bc = 1;
    for (int c = 16; c >= 1; c >>= 1){
        if (ws_size >= (2 + 10 * (size_t)c) * MB) { Bc = c; break; }
    }

    char* ws = (char*)d_ws;
    u16* wT   = (u16*)ws;                      // 1.5 MiB bf16 transposed weights
    float* bqkv = (float*)(ws + 1600*1024);    // fused qkv bias (3 KiB)
    u16* woT  = wT + 196608;
    u16* fc1T = wT + 262144, *fc2T = wT + 524288;
    size_t cb = (size_t)Bc * 2 * MB;
    u16* y    = (u16*)(ws + 2*MB);             // [R][256] bf16      (cb)
    u16* qkvb = (u16*)(ws + 2*MB + cb);        // [R][768] bf16      (3cb)
    u16* lepb = (u16*)(ws + 2*MB + 4*cb);      // [R][256] bf16      (cb)
    u16* hb   = qkvb;                          // MLP hidden [R][1024] overlays qkv+lep

    dim3 blk(256);
    convert_weights_kernel<<<3073, blk, 0, stream>>>(wq, wk, wv, wo, fc1_w, fc2_w,
                                                     bq, bk, bv, wT, bqkv);

    const int nchunk = 16 / Bc;
    const int R = Bc * 4096;                   // rows per chunk
    for (int c = 0; c < nchunk; c++){
        const float* xin = x + (size_t)c * R * 256;
        float* xc = x1 + (size_t)c * R * 256;
        dim3 gqkv(6, R/128), gq(2, R/128), gf(8, R/128);
        posconv_ln1_kernel<<<R/4, blk, 0, stream>>>(xin, pos_w, pos_b, ln1_g, ln1_b, xc, y);
        gemm128_kernel<0><<<gqkv, blk, 0, stream>>>(y, 256, wT, bqkv, nullptr, qkvb, R, 768, 256);
        lepe_kernel<<<Bc*512, blk, 0, stream>>>(qkvb, lepe_w, lepe_b, lepb);
        attn_mfma_kernel<false><<<Bc*64, 512, 0, stream>>>(qkvb, mask_w, nullptr);
        attn_mfma_kernel<true ><<<Bc*64, 512, 0, stream>>>(qkvb, mask_h, lepb);
        // x2 = x1 + attn @ wo + bo   (attn at qkvb+512, stride 768)
        gemm128_kernel<3><<<gq, blk, 0, stream>>>(qkvb + 512, 768, woT, bo, xc, (void*)xc, R, 256, 256);
        ln_kernel<<<R/4, blk, 0, stream>>>(xc, ln2_g, ln2_b, y);
        gemm128_kernel<2><<<gf, blk, 0, stream>>>(y, 256, fc1T, fc1_b, nullptr, hb, R, 1024, 256);
        gemm128_kernel<3><<<gq, blk, 0, stream>>>(hb, 1024, fc2T, fc2_b, xc, (void*)xc, R, 256, 1024);
    }
}